// Round 5
// baseline (563.231 us; speedup 1.0000x reference)
//
#include <hip/hip_runtime.h>

#define L 2048
#define DIM 1024
#define ROWS 8192  // b*l

typedef __attribute__((ext_vector_type(4))) _Float16 v4h;
typedef __attribute__((ext_vector_type(4))) float v4f;
typedef __attribute__((ext_vector_type(8))) short v8s;

#if defined(__HIP_DEVICE_COMPILE__)
#define MFMA_F16_16x16x16(a, b, c) __builtin_amdgcn_mfma_f32_16x16x16f16((a), (b), (c), 0, 0, 0)
#define MFMA_BF16_16x16x32(a, b, c) __builtin_amdgcn_mfma_f32_16x16x32_bf16((a), (b), (c), 0, 0, 0)
#else
#define MFMA_F16_16x16x16(a, b, c) (c)
#define MFMA_BF16_16x16x32(a, b, c) (c)
#endif

__device__ inline unsigned short f2bf(float f) {
  unsigned int u = __float_as_uint(f);
  unsigned int r = (u + 0x7fffu + ((u >> 16) & 1u)) >> 16;
  return (unsigned short)r;
}
__device__ inline void u2_unpack(const uint2 u, float* f) {
  f[0] = __uint_as_float((u.x & 0xffffu) << 16);
  f[1] = __uint_as_float(u.x & 0xffff0000u);
  f[2] = __uint_as_float((u.y & 0xffffu) << 16);
  f[3] = __uint_as_float(u.y & 0xffff0000u);
}
__device__ inline uint4 pack8(const float4 a, const float4 b) {
  uint4 u;
  u.x = (unsigned int)f2bf(a.x) | ((unsigned int)f2bf(a.y) << 16);
  u.y = (unsigned int)f2bf(a.z) | ((unsigned int)f2bf(a.w) << 16);
  u.z = (unsigned int)f2bf(b.x) | ((unsigned int)f2bf(b.y) << 16);
  u.w = (unsigned int)f2bf(b.z) | ((unsigned int)f2bf(b.w) << 16);
  return u;
}

// ---------------------------------------------------------------------------
// GEMM C[M,N] = A[M,K] @ B[N,K]^T. B always fp32 (model weights). A is fp32
// (ABF16=0) or bf16 (ABF16=1). Output fp32 (OUTF32=1) or bf16 (OUTF32=0).
// Internally bf16 MFMA, fp32 accumulate. grid (N/128, M/128), block 256.
// ---------------------------------------------------------------------------
template <int ABF16, int OUTF32>
__global__ __launch_bounds__(256) void gemm_k(const void* __restrict__ Av,
                                              const float* __restrict__ B,
                                              void* __restrict__ Cv) {
  __shared__ __align__(16) unsigned short As[128][40];  // +8 pad
  __shared__ __align__(16) unsigned short Bs[128][40];
  const int tid = threadIdx.x;
  const int bm = blockIdx.y * 128;
  const int bn = blockIdx.x * 128;
  const int wave = tid >> 6;
  const int lane = tid & 63;
  const int m16 = lane & 15;
  const int g = lane >> 4;
  const int wm = (wave >> 1) * 64;
  const int wn = (wave & 1) * 64;
  const int lr = tid >> 2;       // 0..63
  const int lc = (tid & 3) * 8;  // 0,8,16,24

  v4f acc[4][4];
#pragma unroll
  for (int i = 0; i < 4; i++)
#pragma unroll
    for (int j = 0; j < 4; j++) acc[i][j] = (v4f){0.f, 0.f, 0.f, 0.f};

  const float* Bg0 = B + (size_t)(bn + lr) * DIM + lc;
  const float* Bg1 = B + (size_t)(bn + 64 + lr) * DIM + lc;

  for (int kt = 0; kt < DIM; kt += 32) {
    uint4 pa0, pa1;
    if (ABF16) {
      const unsigned short* Af = (const unsigned short*)Av;
      pa0 = *(const uint4*)(Af + (size_t)(bm + lr) * DIM + lc + kt);
      pa1 = *(const uint4*)(Af + (size_t)(bm + 64 + lr) * DIM + lc + kt);
    } else {
      const float* Af = (const float*)Av;
      const float* a0p = Af + (size_t)(bm + lr) * DIM + lc + kt;
      const float* a1p = Af + (size_t)(bm + 64 + lr) * DIM + lc + kt;
      pa0 = pack8(*(const float4*)a0p, *(const float4*)(a0p + 4));
      pa1 = pack8(*(const float4*)a1p, *(const float4*)(a1p + 4));
    }
    const uint4 pb0 = pack8(*(const float4*)(Bg0 + kt), *(const float4*)(Bg0 + kt + 4));
    const uint4 pb1 = pack8(*(const float4*)(Bg1 + kt), *(const float4*)(Bg1 + kt + 4));
    __syncthreads();
    *(uint4*)&As[lr][lc] = pa0;
    *(uint4*)&As[64 + lr][lc] = pa1;
    *(uint4*)&Bs[lr][lc] = pb0;
    *(uint4*)&Bs[64 + lr][lc] = pb1;
    __syncthreads();
    v8s af[4], bf[4];
#pragma unroll
    for (int i = 0; i < 4; i++) af[i] = *(const v8s*)&As[wm + i * 16 + m16][g * 8];
#pragma unroll
    for (int j = 0; j < 4; j++) bf[j] = *(const v8s*)&Bs[wn + j * 16 + m16][g * 8];
#pragma unroll
    for (int i = 0; i < 4; i++)
#pragma unroll
      for (int j = 0; j < 4; j++) acc[i][j] = MFMA_BF16_16x16x32(af[i], bf[j], acc[i][j]);
  }

  // C/D layout: col = m16, row = 4g+e (per 16x16 tile)
#pragma unroll
  for (int i = 0; i < 4; i++)
#pragma unroll
    for (int e = 0; e < 4; e++) {
      const size_t row = (size_t)(bm + wm + i * 16 + 4 * g + e);
#pragma unroll
      for (int j = 0; j < 4; j++) {
        const size_t idx = row * DIM + bn + wn + j * 16 + m16;
        if (OUTF32)
          ((float*)Cv)[idx] = acc[i][j][e];
        else
          ((unsigned short*)Cv)[idx] = f2bf(acc[i][j][e]);
      }
    }
}

// ---------------------------------------------------------------------------
// Fused conv(K=4)+residual+SiLU (+L2norm for q,k) + chunked Titans scan.
// One block per (b,h); 4 waves (wave = d-tile). Raw linears (bf16) staged in
// a 32-row LDS ring for the 3-row causal lookback. W state in C/D fragments
// (C/D layout == B-operand layout; reinterpreted as A it's the transpose).
// ---------------------------------------------------------------------------
__global__ __launch_bounds__(256) void scan_fused(const unsigned short* __restrict__ Qr,
                                                  const unsigned short* __restrict__ Kr,
                                                  const unsigned short* __restrict__ Vr,
                                                  const float* __restrict__ CWq,
                                                  const float* __restrict__ CWk,
                                                  const float* __restrict__ CWv,
                                                  const float* __restrict__ W0,
                                                  unsigned short* __restrict__ O) {
  const int bh = blockIdx.x;
  const int b = bh >> 4;
  const int h = bh & 15;
  const int tid = threadIdx.x;
  const int lane = tid & 63;
  const int dt = tid >> 6;  // wave id == d-tile
  const int m = lane & 15;
  const int g = lane >> 4;

  __shared__ __align__(16) unsigned short rq[32][68];  // raw-linear ring (bf16)
  __shared__ __align__(16) unsigned short rk[32][68];
  __shared__ __align__(16) unsigned short rv[32][68];
  __shared__ __align__(16) _Float16 qs[16][72];
  __shared__ __align__(16) _Float16 ks[16][72];
  __shared__ __align__(16) _Float16 kts[64][20];
  __shared__ __align__(16) _Float16 vts[64][20];

  // W fragment (kt): element e = W[kt*16 + 4g + e][dt*16 + m]
  v4f Wf[4];
#pragma unroll
  for (int kt = 0; kt < 4; kt++)
#pragma unroll
    for (int e = 0; e < 4; e++)
      Wf[kt][e] = W0[(size_t)(h * 64 + kt * 16 + 4 * g + e) * 64 + dt * 16 + m];

  const int srow = tid >> 4;        // 0..15 (time-in-chunk this thread stages)
  const int scol = (tid & 15) * 4;  // 0,4,...,60 (channel quad within head)
  const size_t gcol = (size_t)h * 64 + scol;

  // conv taps for this thread's 4 channels (fp32 inputs)
  float wq[4][4], wk[4][4], wv[4][4];
#pragma unroll
  for (int e = 0; e < 4; e++) {
    const float4 a = *(const float4*)(CWq + (gcol + e) * 4);
    const float4 bq = *(const float4*)(CWk + (gcol + e) * 4);
    const float4 cw = *(const float4*)(CWv + (gcol + e) * 4);
    wq[e][0] = a.x; wq[e][1] = a.y; wq[e][2] = a.z; wq[e][3] = a.w;
    wk[e][0] = bq.x; wk[e][1] = bq.y; wk[e][2] = bq.z; wk[e][3] = bq.w;
    wv[e][0] = cw.x; wv[e][1] = cw.y; wv[e][2] = cw.z; wv[e][3] = cw.w;
  }

  for (int c = 0; c < 128; c++) {
    const int t = c * 16 + srow;
    const size_t gb = ((size_t)(b * L + t)) * DIM + gcol;
    const uint2 qg = *(const uint2*)(Qr + gb);
    const uint2 kg = *(const uint2*)(Kr + gb);
    const uint2 vg = *(const uint2*)(Vr + gb);
    __syncthreads();  // (A) previous chunk done reading ring + staging
    *(uint2*)&rq[t & 31][scol] = qg;
    *(uint2*)&rk[t & 31][scol] = kg;
    *(uint2*)&rv[t & 31][scol] = vg;
    __syncthreads();  // (B) ring visible

    float sq[4], sk[4], sv[4];
    {
      float q0[4], q1[4], q2[4], q3[4];
      float k0[4], k1[4], k2[4], k3[4];
      float v0[4], v1[4], v2[4], v3[4];
      u2_unpack(qg, q0);
      u2_unpack(kg, k0);
      u2_unpack(vg, v0);
      if (t >= 1) { u2_unpack(*(const uint2*)&rq[(t - 1) & 31][scol], q1);
                    u2_unpack(*(const uint2*)&rk[(t - 1) & 31][scol], k1);
                    u2_unpack(*(const uint2*)&rv[(t - 1) & 31][scol], v1); }
      else { for (int e = 0; e < 4; e++) { q1[e] = k1[e] = v1[e] = 0.f; } }
      if (t >= 2) { u2_unpack(*(const uint2*)&rq[(t - 2) & 31][scol], q2);
                    u2_unpack(*(const uint2*)&rk[(t - 2) & 31][scol], k2);
                    u2_unpack(*(const uint2*)&rv[(t - 2) & 31][scol], v2); }
      else { for (int e = 0; e < 4; e++) { q2[e] = k2[e] = v2[e] = 0.f; } }
      if (t >= 3) { u2_unpack(*(const uint2*)&rq[(t - 3) & 31][scol], q3);
                    u2_unpack(*(const uint2*)&rk[(t - 3) & 31][scol], k3);
                    u2_unpack(*(const uint2*)&rv[(t - 3) & 31][scol], v3); }
      else { for (int e = 0; e < 4; e++) { q3[e] = k3[e] = v3[e] = 0.f; } }
#pragma unroll
      for (int e = 0; e < 4; e++) {
        const float yq = q0[e] + wq[e][0] * q3[e] + wq[e][1] * q2[e] + wq[e][2] * q1[e] + wq[e][3] * q0[e];
        const float yk = k0[e] + wk[e][0] * k3[e] + wk[e][1] * k2[e] + wk[e][2] * k1[e] + wk[e][3] * k0[e];
        const float yv = v0[e] + wv[e][0] * v3[e] + wv[e][1] * v2[e] + wv[e][2] * v1[e] + wv[e][3] * v0[e];
        sq[e] = yq / (1.f + __expf(-yq));
        sk[e] = yk / (1.f + __expf(-yk));
        sv[e] = yv / (1.f + __expf(-yv));
      }
    }
    // per-head L2 norm for q,k (16 lanes per row cover the 64 channels)
    float ssq = sq[0] * sq[0] + sq[1] * sq[1] + sq[2] * sq[2] + sq[3] * sq[3];
    float ssk = sk[0] * sk[0] + sk[1] * sk[1] + sk[2] * sk[2] + sk[3] * sk[3];
#pragma unroll
    for (int off = 8; off >= 1; off >>= 1) {
      ssq += __shfl_xor(ssq, off, 16);
      ssk += __shfl_xor(ssk, off, 16);
    }
    const float scq = rsqrtf(ssq + 1e-12f);
    const float sck = rsqrtf(ssk + 1e-12f);

    const v4h qh = {(_Float16)(sq[0] * scq), (_Float16)(sq[1] * scq),
                    (_Float16)(sq[2] * scq), (_Float16)(sq[3] * scq)};
    const v4h kh = {(_Float16)(sk[0] * sck), (_Float16)(sk[1] * sck),
                    (_Float16)(sk[2] * sck), (_Float16)(sk[3] * sck)};
    *(v4h*)&qs[srow][scol] = qh;
    *(v4h*)&ks[srow][scol] = kh;
    kts[scol + 0][srow] = kh[0]; kts[scol + 1][srow] = kh[1];
    kts[scol + 2][srow] = kh[2]; kts[scol + 3][srow] = kh[3];
    vts[scol + 0][srow] = (_Float16)sv[0]; vts[scol + 1][srow] = (_Float16)sv[1];
    vts[scol + 2][srow] = (_Float16)sv[2]; vts[scol + 3][srow] = (_Float16)sv[3];
    __syncthreads();  // (C) staging visible

    v4h qf[4], kf[4], ktf[4];
#pragma unroll
    for (int kt = 0; kt < 4; kt++) {
      qf[kt] = *(const v4h*)&qs[m][kt * 16 + 4 * g];    // A-layout of q / B-layout of q^T
      kf[kt] = *(const v4h*)&ks[m][kt * 16 + 4 * g];    // A-layout of k
      ktf[kt] = *(const v4h*)&kts[kt * 16 + m][4 * g];  // A-layout of k^T
    }
    const v4h vf = *(const v4h*)&vts[dt * 16 + m][4 * g];  // B-layout of v (d-tile)

    // kq = k @ q^T ; this C/D fragment reinterpreted as A IS qk in A-layout
    v4f kq = {0.f, 0.f, 0.f, 0.f};
#pragma unroll
    for (int kt = 0; kt < 4; kt++) kq = MFMA_F16_16x16x16(kf[kt], qf[kt], kq);

    v4h kqA;
#pragma unroll
    for (int e = 0; e < 4; e++)
      kqA[e] = (4 * g + e <= m) ? (_Float16)kq[e] : (_Float16)0.f;

    // o = (tril o qk) @ v + q @ W  (W pre-update)
    v4f of = {0.f, 0.f, 0.f, 0.f};
    of = MFMA_F16_16x16x16(kqA, vf, of);
#pragma unroll
    for (int kt = 0; kt < 4; kt++) {
      v4h Wh;
#pragma unroll
      for (int e = 0; e < 4; e++) Wh[e] = (_Float16)Wf[kt][e];  // C/D == B layout
      of = MFMA_F16_16x16x16(qf[kt], Wh, of);
    }

    // W += k^T @ v
#pragma unroll
    for (int kt = 0; kt < 4; kt++) Wf[kt] = MFMA_F16_16x16x16(ktf[kt], vf, Wf[kt]);

    const size_t ob = ((size_t)(b * L + c * 16 + 4 * g)) * DIM + h * 64 + dt * 16 + m;
#pragma unroll
    for (int e = 0; e < 4; e++) O[ob + (size_t)e * DIM] = f2bf(of[e]);
  }
}

// ---------------------------------------------------------------------------
// LayerNorm over dk=64 per head, then gate multiply. In-place on bf16 O.
// gamma/beta fp32.
// ---------------------------------------------------------------------------
__global__ __launch_bounds__(256) void ln_gate(unsigned short* __restrict__ Ob,
                                               const unsigned short* __restrict__ G,
                                               const float* __restrict__ gamma,
                                               const float* __restrict__ beta) {
  const int r = blockIdx.x;
  const int tid = threadIdx.x;
  const int c = tid * 4;
  float o[4];
  u2_unpack(*(const uint2*)(Ob + (size_t)r * DIM + c), o);
  float sum = o[0] + o[1] + o[2] + o[3];
#pragma unroll
  for (int off = 8; off >= 1; off >>= 1) sum += __shfl_xor(sum, off, 16);
  const float mu = sum * (1.f / 64.f);
  float d[4];
  float vs = 0.f;
#pragma unroll
  for (int e = 0; e < 4; e++) { d[e] = o[e] - mu; vs += d[e] * d[e]; }
#pragma unroll
  for (int off = 8; off >= 1; off >>= 1) vs += __shfl_xor(vs, off, 16);
  const float rstd = rsqrtf(vs * (1.f / 64.f) + 1e-5f);
  const int dl = c & 63;
  const float4 gm = *(const float4*)(gamma + dl);
  const float4 bt = *(const float4*)(beta + dl);
  float gt[4];
  u2_unpack(*(const uint2*)(G + (size_t)r * DIM + c), gt);
  float outv[4];
  outv[0] = (d[0] * rstd * gm.x + bt.x) * gt[0];
  outv[1] = (d[1] * rstd * gm.y + bt.y) * gt[1];
  outv[2] = (d[2] * rstd * gm.z + bt.z) * gt[2];
  outv[3] = (d[3] * rstd * gm.w + bt.w) * gt[3];
  uint2 u;
  u.x = (unsigned int)f2bf(outv[0]) | ((unsigned int)f2bf(outv[1]) << 16);
  u.y = (unsigned int)f2bf(outv[2]) | ((unsigned int)f2bf(outv[3]) << 16);
  *(uint2*)(Ob + (size_t)r * DIM + c) = u;
}

// ---------------------------------------------------------------------------
// fp32 in / fp32 out. bf16 intermediates. Workspace = 2 bf16 slots (32 MB);
// d_out's 32 MB doubles as two more bf16 slots (fully overwritten by the
// final fp32 GEMM, which reads only ws1 + Wo).
// ---------------------------------------------------------------------------
extern "C" void kernel_launch(void* const* d_in, const int* in_sizes, int n_in,
                              void* d_out, int out_size, void* d_ws, size_t ws_size,
                              hipStream_t stream) {
  const float* H  = (const float*)d_in[0];
  const float* Wq = (const float*)d_in[1];
  const float* Wk = (const float*)d_in[2];
  const float* Wv = (const float*)d_in[3];
  const float* cq = (const float*)d_in[4];
  const float* ck = (const float*)d_in[5];
  const float* cv = (const float*)d_in[6];
  const float* W0 = (const float*)d_in[7];
  const float* gamma = (const float*)d_in[8];
  const float* beta  = (const float*)d_in[9];
  const float* Wg = (const float*)d_in[10];
  const float* Wo = (const float*)d_in[11];

  const size_t SZ = (size_t)ROWS * DIM;  // 8M elements
  unsigned short* ws0 = (unsigned short*)d_ws;        // qlin -> gate
  unsigned short* ws1 = ws0 + SZ;                     // o -> o_ln*gate
  unsigned short* do0 = (unsigned short*)d_out;       // klin (scratch)
  unsigned short* do1 = do0 + SZ;                     // vlin (scratch)

  const dim3 gg(DIM / 128, ROWS / 128);
  gemm_k<0, 0><<<gg, 256, 0, stream>>>(H, Wq, ws0);  // q linear (bf16)
  gemm_k<0, 0><<<gg, 256, 0, stream>>>(H, Wk, do0);  // k linear (bf16)
  gemm_k<0, 0><<<gg, 256, 0, stream>>>(H, Wv, do1);  // v linear (bf16)

  scan_fused<<<64, 256, 0, stream>>>(ws0, do0, do1, cq, ck, cv, W0, ws1);

  gemm_k<0, 0><<<gg, 256, 0, stream>>>(H, Wg, ws0);  // gate (qlin dead)

  ln_gate<<<ROWS, 256, 0, stream>>>(ws1, ws0, gamma, beta);

  gemm_k<1, 1><<<gg, 256, 0, stream>>>(ws1, Wo, d_out);  // fp32 output
}

// Round 6
// 406.661 us; speedup vs baseline: 1.3850x; 1.3850x over previous
//
#include <hip/hip_runtime.h>

#define L 2048
#define DIM 1024
#define ROWS 8192     // b*l
#define NSEG 16       // segments per sequence
#define SEG_CHUNKS 8  // chunks per segment
#define SEG_TOK 128   // tokens per segment

typedef __attribute__((ext_vector_type(4))) _Float16 v4h;
typedef __attribute__((ext_vector_type(4))) float v4f;
typedef __attribute__((ext_vector_type(8))) short v8s;

#if defined(__HIP_DEVICE_COMPILE__)
#define MFMA_F16_16x16x16(a, b, c) __builtin_amdgcn_mfma_f32_16x16x16f16((a), (b), (c), 0, 0, 0)
#define MFMA_BF16_16x16x32(a, b, c) __builtin_amdgcn_mfma_f32_16x16x32_bf16((a), (b), (c), 0, 0, 0)
#else
#define MFMA_F16_16x16x16(a, b, c) (c)
#define MFMA_BF16_16x16x32(a, b, c) (c)
#endif

__device__ inline unsigned short f2bf(float f) {
  unsigned int u = __float_as_uint(f);
  unsigned int r = (u + 0x7fffu + ((u >> 16) & 1u)) >> 16;
  return (unsigned short)r;
}
__device__ inline void u2_unpack(const uint2 u, float* f) {  // bf16 x4
  f[0] = __uint_as_float((u.x & 0xffffu) << 16);
  f[1] = __uint_as_float(u.x & 0xffff0000u);
  f[2] = __uint_as_float((u.y & 0xffffu) << 16);
  f[3] = __uint_as_float(u.y & 0xffff0000u);
}
__device__ inline uint4 pack8(const float4 a, const float4 b) {
  uint4 u;
  u.x = (unsigned int)f2bf(a.x) | ((unsigned int)f2bf(a.y) << 16);
  u.y = (unsigned int)f2bf(a.z) | ((unsigned int)f2bf(a.w) << 16);
  u.z = (unsigned int)f2bf(b.x) | ((unsigned int)f2bf(b.y) << 16);
  u.w = (unsigned int)f2bf(b.z) | ((unsigned int)f2bf(b.w) << 16);
  return u;
}
__device__ inline unsigned short f2h_us(float f) {
  _Float16 h = (_Float16)f;
  unsigned short u;
  __builtin_memcpy(&u, &h, 2);
  return u;
}
__device__ inline float h2f_us(unsigned short u) {
  _Float16 h;
  __builtin_memcpy(&h, &u, 2);
  return (float)h;
}
__device__ inline void h4_unpack(const uint2 u, float* f) {  // f16 x4
  f[0] = h2f_us((unsigned short)(u.x & 0xffffu));
  f[1] = h2f_us((unsigned short)(u.x >> 16));
  f[2] = h2f_us((unsigned short)(u.y & 0xffffu));
  f[3] = h2f_us((unsigned short)(u.y >> 16));
}

// ---------------------------------------------------------------------------
// GEMM C[M,N] = A[M,K] @ B[N,K]^T. B fp32 weights; A fp32 (ABF16=0) or bf16
// (ABF16=1); out fp32 (OUTF32=1) or bf16. bf16 MFMA, fp32 accumulate.
// ---------------------------------------------------------------------------
template <int ABF16, int OUTF32>
__global__ __launch_bounds__(256) void gemm_k(const void* __restrict__ Av,
                                              const float* __restrict__ B,
                                              void* __restrict__ Cv) {
  __shared__ __align__(16) unsigned short As[128][40];
  __shared__ __align__(16) unsigned short Bs[128][40];
  const int tid = threadIdx.x;
  const int bm = blockIdx.y * 128;
  const int bn = blockIdx.x * 128;
  const int wave = tid >> 6;
  const int lane = tid & 63;
  const int m16 = lane & 15;
  const int g = lane >> 4;
  const int wm = (wave >> 1) * 64;
  const int wn = (wave & 1) * 64;
  const int lr = tid >> 2;
  const int lc = (tid & 3) * 8;

  v4f acc[4][4];
#pragma unroll
  for (int i = 0; i < 4; i++)
#pragma unroll
    for (int j = 0; j < 4; j++) acc[i][j] = (v4f){0.f, 0.f, 0.f, 0.f};

  const float* Bg0 = B + (size_t)(bn + lr) * DIM + lc;
  const float* Bg1 = B + (size_t)(bn + 64 + lr) * DIM + lc;

  for (int kt = 0; kt < DIM; kt += 32) {
    uint4 pa0, pa1;
    if (ABF16) {
      const unsigned short* Af = (const unsigned short*)Av;
      pa0 = *(const uint4*)(Af + (size_t)(bm + lr) * DIM + lc + kt);
      pa1 = *(const uint4*)(Af + (size_t)(bm + 64 + lr) * DIM + lc + kt);
    } else {
      const float* Af = (const float*)Av;
      const float* a0p = Af + (size_t)(bm + lr) * DIM + lc + kt;
      const float* a1p = Af + (size_t)(bm + 64 + lr) * DIM + lc + kt;
      pa0 = pack8(*(const float4*)a0p, *(const float4*)(a0p + 4));
      pa1 = pack8(*(const float4*)a1p, *(const float4*)(a1p + 4));
    }
    const uint4 pb0 = pack8(*(const float4*)(Bg0 + kt), *(const float4*)(Bg0 + kt + 4));
    const uint4 pb1 = pack8(*(const float4*)(Bg1 + kt), *(const float4*)(Bg1 + kt + 4));
    __syncthreads();
    *(uint4*)&As[lr][lc] = pa0;
    *(uint4*)&As[64 + lr][lc] = pa1;
    *(uint4*)&Bs[lr][lc] = pb0;
    *(uint4*)&Bs[64 + lr][lc] = pb1;
    __syncthreads();
    v8s af[4], bf[4];
#pragma unroll
    for (int i = 0; i < 4; i++) af[i] = *(const v8s*)&As[wm + i * 16 + m16][g * 8];
#pragma unroll
    for (int j = 0; j < 4; j++) bf[j] = *(const v8s*)&Bs[wn + j * 16 + m16][g * 8];
#pragma unroll
    for (int i = 0; i < 4; i++)
#pragma unroll
      for (int j = 0; j < 4; j++) acc[i][j] = MFMA_BF16_16x16x32(af[i], bf[j], acc[i][j]);
  }

#pragma unroll
  for (int i = 0; i < 4; i++)
#pragma unroll
    for (int e = 0; e < 4; e++) {
      const size_t row = (size_t)(bm + wm + i * 16 + 4 * g + e);
#pragma unroll
      for (int j = 0; j < 4; j++) {
        const size_t idx = row * DIM + bn + wn + j * 16 + m16;
        if (OUTF32)
          ((float*)Cv)[idx] = acc[i][j][e];
        else
          ((unsigned short*)Cv)[idx] = f2bf(acc[i][j][e]);
      }
    }
}

// ---------------------------------------------------------------------------
// Copy the 3 pre-segment boundary rows of raw q/k/v linears to a side buffer
// (zeros for seg 0) so segmented scan blocks never race on in-place writes.
// grid 192 = (b*16+seg)*3 + j, block 256.
// ---------------------------------------------------------------------------
__global__ __launch_bounds__(256) void copy_side(const unsigned short* __restrict__ Q,
                                                 const unsigned short* __restrict__ K,
                                                 const unsigned short* __restrict__ V,
                                                 unsigned short* __restrict__ sQ,
                                                 unsigned short* __restrict__ sK,
                                                 unsigned short* __restrict__ sV) {
  const int idx = blockIdx.x;
  const int j = idx % 3;
  const int bs = idx / 3;  // b*16+seg
  const int seg = bs & 15;
  const int b = bs >> 4;
  const int ch = threadIdx.x * 4;
  const size_t so = ((size_t)(bs * 3 + j)) * DIM + ch;
  if (seg == 0) {
    const uint2 z = {0u, 0u};
    *(uint2*)(sQ + so) = z;
    *(uint2*)(sK + so) = z;
    *(uint2*)(sV + so) = z;
  } else {
    const size_t go = ((size_t)(b * L + seg * SEG_TOK - 3 + j)) * DIM + ch;
    *(uint2*)(sQ + so) = *(const uint2*)(Q + go);
    *(uint2*)(sK + so) = *(const uint2*)(K + go);
    *(uint2*)(sV + so) = *(const uint2*)(V + go);
  }
}

// ---------------------------------------------------------------------------
// Phase A: segmented fused conv+SiLU(+L2norm) + local Titans scan from W=0.
// grid 1024 = (b,h,seg); block 256 (4 waves = d-tiles). Writes qc (f16,
// in-place over Qr), o_partial (f16, in-place over Vr), and the segment's
// K^TV total D (fp32) for the global prefix.
// ---------------------------------------------------------------------------
__global__ __launch_bounds__(256) void scan_seg(unsigned short* __restrict__ Qr,
                                                const unsigned short* __restrict__ Kr,
                                                unsigned short* __restrict__ Vr,
                                                const unsigned short* __restrict__ sQ,
                                                const unsigned short* __restrict__ sK,
                                                const unsigned short* __restrict__ sV,
                                                const float* __restrict__ CWq,
                                                const float* __restrict__ CWk,
                                                const float* __restrict__ CWv,
                                                float* __restrict__ D) {
  const int seg = blockIdx.x & 15;
  const int h = (blockIdx.x >> 4) & 15;
  const int b = blockIdx.x >> 8;
  const int tid = threadIdx.x;
  const int lane = tid & 63;
  const int dt = tid >> 6;
  const int m = lane & 15;
  const int g = lane >> 4;
  const int segbase = seg * SEG_TOK;

  __shared__ __align__(16) unsigned short rq[32][68];
  __shared__ __align__(16) unsigned short rk[32][68];
  __shared__ __align__(16) unsigned short rv[32][68];
  __shared__ __align__(16) _Float16 qs[16][72];
  __shared__ __align__(16) _Float16 ks[16][72];
  __shared__ __align__(16) _Float16 kts[64][20];
  __shared__ __align__(16) _Float16 vts[64][20];

  v4f Wf[4];
#pragma unroll
  for (int kt = 0; kt < 4; kt++) Wf[kt] = (v4f){0.f, 0.f, 0.f, 0.f};

  const int srow = tid >> 4;
  const int scol = (tid & 15) * 4;
  const size_t gcol = (size_t)h * 64 + scol;

  float wq[4][4], wk[4][4], wv[4][4];
#pragma unroll
  for (int e = 0; e < 4; e++) {
    const float4 a = *(const float4*)(CWq + (gcol + e) * 4);
    const float4 bw = *(const float4*)(CWk + (gcol + e) * 4);
    const float4 cw = *(const float4*)(CWv + (gcol + e) * 4);
    wq[e][0] = a.x; wq[e][1] = a.y; wq[e][2] = a.z; wq[e][3] = a.w;
    wk[e][0] = bw.x; wk[e][1] = bw.y; wk[e][2] = bw.z; wk[e][3] = bw.w;
    wv[e][0] = cw.x; wv[e][1] = cw.y; wv[e][2] = cw.z; wv[e][3] = cw.w;
  }

  // preload boundary rows into ring slots 29..31
  if (tid < 48) {
    const int j = tid >> 4;
    const int sc = (tid & 15) * 4;
    const size_t so = ((size_t)((b * NSEG + seg) * 3 + j)) * DIM + h * 64 + sc;
    const int slot = (29 + j);
    *(uint2*)&rq[slot][sc] = *(const uint2*)(sQ + so);
    *(uint2*)&rk[slot][sc] = *(const uint2*)(sK + so);
    *(uint2*)&rv[slot][sc] = *(const uint2*)(sV + so);
  }

  size_t gb = ((size_t)(b * L + segbase + srow)) * DIM + gcol;
  uint2 qg = *(const uint2*)(Qr + gb);
  uint2 kg = *(const uint2*)(Kr + gb);
  uint2 vg = *(const uint2*)(Vr + gb);

  for (int c = 0; c < SEG_CHUNKS; c++) {
    const int t = segbase + c * 16 + srow;
    __syncthreads();  // (A) previous chunk done with ring + staging
    *(uint2*)&rq[t & 31][scol] = qg;
    *(uint2*)&rk[t & 31][scol] = kg;
    *(uint2*)&rv[t & 31][scol] = vg;
    // prefetch next chunk (clamped; same-thread same-address at c=7 is safe)
    const int cn = (c + 1 < SEG_CHUNKS) ? c + 1 : c;
    const size_t gbn = ((size_t)(b * L + segbase + cn * 16 + srow)) * DIM + gcol;
    const uint2 qn = *(const uint2*)(Qr + gbn);
    const uint2 kn = *(const uint2*)(Kr + gbn);
    const uint2 vn = *(const uint2*)(Vr + gbn);
    __syncthreads();  // (B) ring visible

    float sq[4], sk[4], sv[4];
    {
      float q0[4], q1[4], q2[4], q3[4];
      float k0[4], k1[4], k2[4], k3[4];
      float v0[4], v1[4], v2[4], v3[4];
      u2_unpack(qg, q0);
      u2_unpack(kg, k0);
      u2_unpack(vg, v0);
      u2_unpack(*(const uint2*)&rq[(t - 1) & 31][scol], q1);
      u2_unpack(*(const uint2*)&rk[(t - 1) & 31][scol], k1);
      u2_unpack(*(const uint2*)&rv[(t - 1) & 31][scol], v1);
      u2_unpack(*(const uint2*)&rq[(t - 2) & 31][scol], q2);
      u2_unpack(*(const uint2*)&rk[(t - 2) & 31][scol], k2);
      u2_unpack(*(const uint2*)&rv[(t - 2) & 31][scol], v2);
      u2_unpack(*(const uint2*)&rq[(t - 3) & 31][scol], q3);
      u2_unpack(*(const uint2*)&rk[(t - 3) & 31][scol], k3);
      u2_unpack(*(const uint2*)&rv[(t - 3) & 31][scol], v3);
#pragma unroll
      for (int e = 0; e < 4; e++) {
        const float yq = q0[e] + wq[e][0] * q3[e] + wq[e][1] * q2[e] + wq[e][2] * q1[e] + wq[e][3] * q0[e];
        const float yk = k0[e] + wk[e][0] * k3[e] + wk[e][1] * k2[e] + wk[e][2] * k1[e] + wk[e][3] * k0[e];
        const float yv = v0[e] + wv[e][0] * v3[e] + wv[e][1] * v2[e] + wv[e][2] * v1[e] + wv[e][3] * v0[e];
        sq[e] = yq / (1.f + __expf(-yq));
        sk[e] = yk / (1.f + __expf(-yk));
        sv[e] = yv / (1.f + __expf(-yv));
      }
    }
    float ssq = sq[0] * sq[0] + sq[1] * sq[1] + sq[2] * sq[2] + sq[3] * sq[3];
    float ssk = sk[0] * sk[0] + sk[1] * sk[1] + sk[2] * sk[2] + sk[3] * sk[3];
#pragma unroll
    for (int off = 8; off >= 1; off >>= 1) {
      ssq += __shfl_xor(ssq, off, 16);
      ssk += __shfl_xor(ssk, off, 16);
    }
    const float scq = rsqrtf(ssq + 1e-12f);
    const float sck = rsqrtf(ssk + 1e-12f);

    const v4h qh = {(_Float16)(sq[0] * scq), (_Float16)(sq[1] * scq),
                    (_Float16)(sq[2] * scq), (_Float16)(sq[3] * scq)};
    const v4h kh = {(_Float16)(sk[0] * sck), (_Float16)(sk[1] * sck),
                    (_Float16)(sk[2] * sck), (_Float16)(sk[3] * sck)};
    *(v4h*)&qs[srow][scol] = qh;
    *(v4h*)&ks[srow][scol] = kh;
    kts[scol + 0][srow] = kh[0]; kts[scol + 1][srow] = kh[1];
    kts[scol + 2][srow] = kh[2]; kts[scol + 3][srow] = kh[3];
    vts[scol + 0][srow] = (_Float16)sv[0]; vts[scol + 1][srow] = (_Float16)sv[1];
    vts[scol + 2][srow] = (_Float16)sv[2]; vts[scol + 3][srow] = (_Float16)sv[3];

    // write qc (f16) in place over Qr for phase C
    uint2 qp;
    __builtin_memcpy(&qp, &qh, 8);
    *(uint2*)(Qr + gb) = qp;

    __syncthreads();  // (C) staging visible

    v4h qf[4], kf[4], ktf[4];
#pragma unroll
    for (int kt = 0; kt < 4; kt++) {
      qf[kt] = *(const v4h*)&qs[m][kt * 16 + 4 * g];
      kf[kt] = *(const v4h*)&ks[m][kt * 16 + 4 * g];
      ktf[kt] = *(const v4h*)&kts[kt * 16 + m][4 * g];
    }
    const v4h vf = *(const v4h*)&vts[dt * 16 + m][4 * g];

    v4f kq = {0.f, 0.f, 0.f, 0.f};
#pragma unroll
    for (int kt = 0; kt < 4; kt++) kq = MFMA_F16_16x16x16(kf[kt], qf[kt], kq);

    v4h kqA;
#pragma unroll
    for (int e = 0; e < 4; e++)
      kqA[e] = (4 * g + e <= m) ? (_Float16)kq[e] : (_Float16)0.f;

    v4f of = {0.f, 0.f, 0.f, 0.f};
    of = MFMA_F16_16x16x16(kqA, vf, of);
#pragma unroll
    for (int kt = 0; kt < 4; kt++) {
      v4h Wh;
#pragma unroll
      for (int e = 0; e < 4; e++) Wh[e] = (_Float16)Wf[kt][e];
      of = MFMA_F16_16x16x16(qf[kt], Wh, of);
    }
#pragma unroll
    for (int kt = 0; kt < 4; kt++) Wf[kt] = MFMA_F16_16x16x16(ktf[kt], vf, Wf[kt]);

    const size_t ob = ((size_t)(b * L + segbase + c * 16 + 4 * g)) * DIM + h * 64 + dt * 16 + m;
#pragma unroll
    for (int e = 0; e < 4; e++) Vr[ob + (size_t)e * DIM] = f2h_us(of[e]);

    qg = qn; kg = kn; vg = vn; gb = gbn;
  }

  // store segment delta D (fp32): row = kt*16+4g+e, col = dt*16+m
  float* Dp = D + ((size_t)((b * 16 + h) * NSEG + seg)) * 4096;
#pragma unroll
  for (int kt = 0; kt < 4; kt++)
#pragma unroll
    for (int e = 0; e < 4; e++)
      Dp[(kt * 16 + 4 * g + e) * 64 + dt * 16 + m] = Wf[kt][e];
}

// ---------------------------------------------------------------------------
// Phase B: in-place exclusive prefix over segments, seeded with W0.
// grid 64 = (b,h); block 256; each thread owns 16 elements.
// ---------------------------------------------------------------------------
__global__ __launch_bounds__(256) void prefix_D(float* __restrict__ D,
                                                const float* __restrict__ W0) {
  const int bh = blockIdx.x;
  const int h = bh & 15;
  const int tid = threadIdx.x;
  float p[16];
#pragma unroll
  for (int i = 0; i < 16; i++) p[i] = W0[(size_t)h * 4096 + tid + i * 256];
  for (int s = 0; s < NSEG; s++) {
    float* Dp = D + ((size_t)bh * NSEG + s) * 4096;
#pragma unroll
    for (int i = 0; i < 16; i++) {
      const float t = Dp[tid + i * 256];
      Dp[tid + i * 256] = p[i];
      p[i] += t;
    }
  }
}

// ---------------------------------------------------------------------------
// Phase C: o += qc @ P_seg. grid 1024 = (b,h,seg); block 256 (4 waves).
// ---------------------------------------------------------------------------
__global__ __launch_bounds__(256) void apply_corr(const unsigned short* __restrict__ Qc,
                                                  const float* __restrict__ P,
                                                  unsigned short* __restrict__ Op) {
  const int seg = blockIdx.x & 15;
  const int h = (blockIdx.x >> 4) & 15;
  const int b = blockIdx.x >> 8;
  const int tid = threadIdx.x;
  const int lane = tid & 63;
  const int dt = tid >> 6;
  const int m = lane & 15;
  const int g = lane >> 4;

  __shared__ __align__(16) _Float16 Pt[64][72];  // transposed: Pt[col][row]
  __shared__ __align__(16) _Float16 qt[16][72];

  const float* Pp = P + ((size_t)((b * 16 + h) * NSEG + seg)) * 4096;
#pragma unroll
  for (int i = 0; i < 16; i++) {
    const int el = tid + i * 256;
    Pt[el & 63][el >> 6] = (_Float16)Pp[el];
  }
  __syncthreads();

  // B-frags of P: pb[kt][e] = P[kt*16+4g+e][dt*16+m] = Pt[dt*16+m][kt*16+4g+e]
  v4h pb[4];
#pragma unroll
  for (int kt = 0; kt < 4; kt++) pb[kt] = *(const v4h*)&Pt[dt * 16 + m][kt * 16 + 4 * g];

  const int srow = tid >> 4;
  const int scol = (tid & 15) * 4;
  for (int rt = 0; rt < 8; rt++) {
    const size_t gb = ((size_t)(b * L + seg * SEG_TOK + rt * 16 + srow)) * DIM + h * 64 + scol;
    const uint2 qg = *(const uint2*)(Qc + gb);
    __syncthreads();  // previous tile's frag reads done
    *(uint2*)&qt[srow][scol] = qg;
    __syncthreads();
    v4h qf[4];
#pragma unroll
    for (int kt = 0; kt < 4; kt++) qf[kt] = *(const v4h*)&qt[m][kt * 16 + 4 * g];
    v4f corr = {0.f, 0.f, 0.f, 0.f};
#pragma unroll
    for (int kt = 0; kt < 4; kt++) corr = MFMA_F16_16x16x16(qf[kt], pb[kt], corr);
    const size_t ob = ((size_t)(b * L + seg * SEG_TOK + rt * 16 + 4 * g)) * DIM + h * 64 + dt * 16 + m;
#pragma unroll
    for (int e = 0; e < 4; e++) {
      const float v = h2f_us(Op[ob + (size_t)e * DIM]) + corr[e];
      Op[ob + (size_t)e * DIM] = f2h_us(v);
    }
  }
}

// ---------------------------------------------------------------------------
// LayerNorm over dk=64 per head, then gate multiply. O f16 in, bf16 out
// (in place); gate bf16; gamma/beta fp32.
// ---------------------------------------------------------------------------
__global__ __launch_bounds__(256) void ln_gate(unsigned short* __restrict__ Ob,
                                               const unsigned short* __restrict__ G,
                                               const float* __restrict__ gamma,
                                               const float* __restrict__ beta) {
  const int r = blockIdx.x;
  const int tid = threadIdx.x;
  const int c = tid * 4;
  float o[4];
  h4_unpack(*(const uint2*)(Ob + (size_t)r * DIM + c), o);
  float sum = o[0] + o[1] + o[2] + o[3];
#pragma unroll
  for (int off = 8; off >= 1; off >>= 1) sum += __shfl_xor(sum, off, 16);
  const float mu = sum * (1.f / 64.f);
  float d[4];
  float vs = 0.f;
#pragma unroll
  for (int e = 0; e < 4; e++) { d[e] = o[e] - mu; vs += d[e] * d[e]; }
#pragma unroll
  for (int off = 8; off >= 1; off >>= 1) vs += __shfl_xor(vs, off, 16);
  const float rstd = rsqrtf(vs * (1.f / 64.f) + 1e-5f);
  const int dl = c & 63;
  const float4 gm = *(const float4*)(gamma + dl);
  const float4 bt = *(const float4*)(beta + dl);
  float gt[4];
  u2_unpack(*(const uint2*)(G + (size_t)r * DIM + c), gt);
  float outv[4];
  outv[0] = (d[0] * rstd * gm.x + bt.x) * gt[0];
  outv[1] = (d[1] * rstd * gm.y + bt.y) * gt[1];
  outv[2] = (d[2] * rstd * gm.z + bt.z) * gt[2];
  outv[3] = (d[3] * rstd * gm.w + bt.w) * gt[3];
  uint2 u;
  u.x = (unsigned int)f2bf(outv[0]) | ((unsigned int)f2bf(outv[1]) << 16);
  u.y = (unsigned int)f2bf(outv[2]) | ((unsigned int)f2bf(outv[3]) << 16);
  *(uint2*)(Ob + (size_t)r * DIM + c) = u;
}

// ---------------------------------------------------------------------------
// ws (48 MB): sA=qlin->qc(f16), sB=klin->gate, sC=vlin->o_part(f16)->o_ln(bf16)
// d_out (32 MB): D/P (16 MB) + side (1.2 MB @ +17 MB); final fp32 GEMM
// overwrites all of d_out last.
// ---------------------------------------------------------------------------
extern "C" void kernel_launch(void* const* d_in, const int* in_sizes, int n_in,
                              void* d_out, int out_size, void* d_ws, size_t ws_size,
                              hipStream_t stream) {
  const float* H  = (const float*)d_in[0];
  const float* Wq = (const float*)d_in[1];
  const float* Wk = (const float*)d_in[2];
  const float* Wv = (const float*)d_in[3];
  const float* cq = (const float*)d_in[4];
  const float* ck = (const float*)d_in[5];
  const float* cv = (const float*)d_in[6];
  const float* W0 = (const float*)d_in[7];
  const float* gamma = (const float*)d_in[8];
  const float* beta  = (const float*)d_in[9];
  const float* Wg = (const float*)d_in[10];
  const float* Wo = (const float*)d_in[11];

  const size_t SZ = (size_t)ROWS * DIM;
  unsigned short* sA = (unsigned short*)d_ws;
  unsigned short* sB = sA + SZ;
  unsigned short* sC = sB + SZ;
  float* D = (float*)d_out;
  unsigned short* side = (unsigned short*)((char*)d_out + (17u << 20));
  unsigned short* sideQ = side;
  unsigned short* sideK = side + (size_t)192 * DIM;
  unsigned short* sideV = side + (size_t)384 * DIM;

  const dim3 gg(DIM / 128, ROWS / 128);
  gemm_k<0, 0><<<gg, 256, 0, stream>>>(H, Wq, sA);  // qlin (bf16)
  gemm_k<0, 0><<<gg, 256, 0, stream>>>(H, Wk, sB);  // klin (bf16)
  gemm_k<0, 0><<<gg, 256, 0, stream>>>(H, Wv, sC);  // vlin (bf16)

  copy_side<<<192, 256, 0, stream>>>(sA, sB, sC, sideQ, sideK, sideV);

  scan_seg<<<1024, 256, 0, stream>>>(sA, sB, sC, sideQ, sideK, sideV,
                                     cq, ck, cv, D);

  gemm_k<0, 0><<<gg, 256, 0, stream>>>(H, Wg, sB);  // gate (klin dead)

  prefix_D<<<64, 256, 0, stream>>>(D, W0);

  apply_corr<<<1024, 256, 0, stream>>>(sA, D, sC);

  ln_gate<<<ROWS, 256, 0, stream>>>(sC, sB, gamma, beta);

  gemm_k<1, 1><<<gg, 256, 0, stream>>>(sC, Wo, d_out);
}

// Round 7
// 344.376 us; speedup vs baseline: 1.6355x; 1.1809x over previous
//
#include <hip/hip_runtime.h>

#define L 2048
#define DIM 1024
#define ROWS 8192     // b*l
#define NSEG 16       // segments per sequence
#define SEG_CHUNKS 8  // chunks per segment
#define SEG_TOK 128   // tokens per segment

typedef __attribute__((ext_vector_type(4))) _Float16 v4h;
typedef __attribute__((ext_vector_type(4))) float v4f;
typedef __attribute__((ext_vector_type(8))) short v8s;

#if defined(__HIP_DEVICE_COMPILE__)
#define MFMA_F16_16x16x16(a, b, c) __builtin_amdgcn_mfma_f32_16x16x16f16((a), (b), (c), 0, 0, 0)
#define MFMA_BF16_16x16x32(a, b, c) __builtin_amdgcn_mfma_f32_16x16x32_bf16((a), (b), (c), 0, 0, 0)
#else
#define MFMA_F16_16x16x16(a, b, c) (c)
#define MFMA_BF16_16x16x32(a, b, c) (c)
#endif

__device__ inline unsigned short f2bf(float f) {
  unsigned int u = __float_as_uint(f);
  unsigned int r = (u + 0x7fffu + ((u >> 16) & 1u)) >> 16;
  return (unsigned short)r;
}
__device__ inline void u2_unpack(const uint2 u, float* f) {  // bf16 x4
  f[0] = __uint_as_float((u.x & 0xffffu) << 16);
  f[1] = __uint_as_float(u.x & 0xffff0000u);
  f[2] = __uint_as_float((u.y & 0xffffu) << 16);
  f[3] = __uint_as_float(u.y & 0xffff0000u);
}
__device__ inline uint4 pack8(const float4 a, const float4 b) {
  uint4 u;
  u.x = (unsigned int)f2bf(a.x) | ((unsigned int)f2bf(a.y) << 16);
  u.y = (unsigned int)f2bf(a.z) | ((unsigned int)f2bf(a.w) << 16);
  u.z = (unsigned int)f2bf(b.x) | ((unsigned int)f2bf(b.y) << 16);
  u.w = (unsigned int)f2bf(b.z) | ((unsigned int)f2bf(b.w) << 16);
  return u;
}
__device__ inline unsigned short f2h_us(float f) {
  _Float16 h = (_Float16)f;
  unsigned short u;
  __builtin_memcpy(&u, &h, 2);
  return u;
}
__device__ inline float h2f_us(unsigned short u) {
  _Float16 h;
  __builtin_memcpy(&h, &u, 2);
  return (float)h;
}
__device__ inline void h4_unpack(const uint2 u, float* f) {  // f16 x4
  f[0] = h2f_us((unsigned short)(u.x & 0xffffu));
  f[1] = h2f_us((unsigned short)(u.x >> 16));
  f[2] = h2f_us((unsigned short)(u.y & 0xffffu));
  f[3] = h2f_us((unsigned short)(u.y >> 16));
}

// ---------------------------------------------------------------------------
// fp32 -> bf16 converters
// ---------------------------------------------------------------------------
__global__ __launch_bounds__(256) void cvt_f2b(const float* __restrict__ s,
                                               unsigned short* __restrict__ d) {
  const int i = blockIdx.x * 256 + threadIdx.x;  // one float4 per thread
  const float4 v = ((const float4*)s)[i];
  uint2 u;
  u.x = (unsigned int)f2bf(v.x) | ((unsigned int)f2bf(v.y) << 16);
  u.y = (unsigned int)f2bf(v.z) | ((unsigned int)f2bf(v.w) << 16);
  ((uint2*)d)[i] = u;
}

__global__ __launch_bounds__(256) void cvt_w4(const float* __restrict__ w0,
                                              const float* __restrict__ w1,
                                              const float* __restrict__ w2,
                                              const float* __restrict__ w3,
                                              unsigned short* __restrict__ dst) {
  const int t = blockIdx.x >> 10;  // 0..3 which weight
  const int i = (blockIdx.x & 1023) * 256 + threadIdx.x;
  const float* s = (t == 0) ? w0 : (t == 1) ? w1 : (t == 2) ? w2 : w3;
  const float4 v = ((const float4*)s)[i];
  uint2 u;
  u.x = (unsigned int)f2bf(v.x) | ((unsigned int)f2bf(v.y) << 16);
  u.y = (unsigned int)f2bf(v.z) | ((unsigned int)f2bf(v.w) << 16);
  ((uint2*)(dst + (size_t)t * DIM * DIM))[i] = u;
}

// ---------------------------------------------------------------------------
// GEMM C[M,N] = A[M,K] @ B[N,K]^T. A/B bf16 (direct) or fp32 (pack in
// staging); out fp32 or bf16. bf16 MFMA, fp32 acc. 128x128 tile, BK=32,
// register prefetch of next K-tile.
// ---------------------------------------------------------------------------
template <int ABF16, int BBF16, int OUTF32>
__global__ __launch_bounds__(256) void gemm_t(const void* __restrict__ Av,
                                              const void* __restrict__ Bv,
                                              void* __restrict__ Cv) {
  __shared__ __align__(16) unsigned short As[128][40];
  __shared__ __align__(16) unsigned short Bs[128][40];
  const int tid = threadIdx.x;
  const int bm = blockIdx.y * 128;
  const int bn = blockIdx.x * 128;
  const int wave = tid >> 6;
  const int lane = tid & 63;
  const int m16 = lane & 15;
  const int g = lane >> 4;
  const int wm = (wave >> 1) * 64;
  const int wn = (wave & 1) * 64;
  const int lr = tid >> 2;
  const int lc = (tid & 3) * 8;

  v4f acc[4][4];
#pragma unroll
  for (int i = 0; i < 4; i++)
#pragma unroll
    for (int j = 0; j < 4; j++) acc[i][j] = (v4f){0.f, 0.f, 0.f, 0.f};

  auto loadAB = [&](int kt, uint4& a0, uint4& a1, uint4& b0, uint4& b1) {
    if (ABF16) {
      const unsigned short* Af = (const unsigned short*)Av;
      a0 = *(const uint4*)(Af + (size_t)(bm + lr) * DIM + lc + kt);
      a1 = *(const uint4*)(Af + (size_t)(bm + 64 + lr) * DIM + lc + kt);
    } else {
      const float* Af = (const float*)Av;
      const float* p0 = Af + (size_t)(bm + lr) * DIM + lc + kt;
      const float* p1 = Af + (size_t)(bm + 64 + lr) * DIM + lc + kt;
      a0 = pack8(*(const float4*)p0, *(const float4*)(p0 + 4));
      a1 = pack8(*(const float4*)p1, *(const float4*)(p1 + 4));
    }
    if (BBF16) {
      const unsigned short* Bf = (const unsigned short*)Bv;
      b0 = *(const uint4*)(Bf + (size_t)(bn + lr) * DIM + lc + kt);
      b1 = *(const uint4*)(Bf + (size_t)(bn + 64 + lr) * DIM + lc + kt);
    } else {
      const float* Bf = (const float*)Bv;
      const float* p0 = Bf + (size_t)(bn + lr) * DIM + lc + kt;
      const float* p1 = Bf + (size_t)(bn + 64 + lr) * DIM + lc + kt;
      b0 = pack8(*(const float4*)p0, *(const float4*)(p0 + 4));
      b1 = pack8(*(const float4*)p1, *(const float4*)(p1 + 4));
    }
  };

  uint4 a0, a1, b0, b1;
  loadAB(0, a0, a1, b0, b1);

  for (int kt = 0; kt < DIM; kt += 32) {
    __syncthreads();  // previous iter's LDS readers done
    *(uint4*)&As[lr][lc] = a0;
    *(uint4*)&As[64 + lr][lc] = a1;
    *(uint4*)&Bs[lr][lc] = b0;
    *(uint4*)&Bs[64 + lr][lc] = b1;
    __syncthreads();
    if (kt + 32 < DIM) loadAB(kt + 32, a0, a1, b0, b1);  // prefetch next tile
    v8s af[4], bf[4];
#pragma unroll
    for (int i = 0; i < 4; i++) af[i] = *(const v8s*)&As[wm + i * 16 + m16][g * 8];
#pragma unroll
    for (int j = 0; j < 4; j++) bf[j] = *(const v8s*)&Bs[wn + j * 16 + m16][g * 8];
#pragma unroll
    for (int i = 0; i < 4; i++)
#pragma unroll
      for (int j = 0; j < 4; j++) acc[i][j] = MFMA_BF16_16x16x32(af[i], bf[j], acc[i][j]);
  }

  // C/D layout: col = m16, row = 4g+e (per 16x16 tile)
#pragma unroll
  for (int i = 0; i < 4; i++)
#pragma unroll
    for (int e = 0; e < 4; e++) {
      const size_t row = (size_t)(bm + wm + i * 16 + 4 * g + e);
#pragma unroll
      for (int j = 0; j < 4; j++) {
        const size_t idx = row * DIM + bn + wn + j * 16 + m16;
        if (OUTF32)
          ((float*)Cv)[idx] = acc[i][j][e];
        else
          ((unsigned short*)Cv)[idx] = f2bf(acc[i][j][e]);
      }
    }
}

// ---------------------------------------------------------------------------
// Copy 3 pre-segment boundary rows of raw q/k/v linears to a side buffer
// (zeros for seg 0). grid 192, block 256.
// ---------------------------------------------------------------------------
__global__ __launch_bounds__(256) void copy_side(const unsigned short* __restrict__ Q,
                                                 const unsigned short* __restrict__ K,
                                                 const unsigned short* __restrict__ V,
                                                 unsigned short* __restrict__ sQ,
                                                 unsigned short* __restrict__ sK,
                                                 unsigned short* __restrict__ sV) {
  const int idx = blockIdx.x;
  const int j = idx % 3;
  const int bs = idx / 3;  // b*16+seg
  const int seg = bs & 15;
  const int b = bs >> 4;
  const int ch = threadIdx.x * 4;
  const size_t so = ((size_t)(bs * 3 + j)) * DIM + ch;
  if (seg == 0) {
    const uint2 z = {0u, 0u};
    *(uint2*)(sQ + so) = z;
    *(uint2*)(sK + so) = z;
    *(uint2*)(sV + so) = z;
  } else {
    const size_t go = ((size_t)(b * L + seg * SEG_TOK - 3 + j)) * DIM + ch;
    *(uint2*)(sQ + so) = *(const uint2*)(Q + go);
    *(uint2*)(sK + so) = *(const uint2*)(K + go);
    *(uint2*)(sV + so) = *(const uint2*)(V + go);
  }
}

// ---------------------------------------------------------------------------
// Phase A: segmented fused conv+SiLU(+L2norm) + local Titans scan from W=0.
// grid 1024 = (b,h,seg); block 256. Writes qc (f16 in-place over Qr),
// o_partial (f16 in-place over Vr), segment delta D (fp32).
// ---------------------------------------------------------------------------
__global__ __launch_bounds__(256) void scan_seg(unsigned short* __restrict__ Qr,
                                                const unsigned short* __restrict__ Kr,
                                                unsigned short* __restrict__ Vr,
                                                const unsigned short* __restrict__ sQ,
                                                const unsigned short* __restrict__ sK,
                                                const unsigned short* __restrict__ sV,
                                                const float* __restrict__ CWq,
                                                const float* __restrict__ CWk,
                                                const float* __restrict__ CWv,
                                                float* __restrict__ D) {
  const int seg = blockIdx.x & 15;
  const int h = (blockIdx.x >> 4) & 15;
  const int b = blockIdx.x >> 8;
  const int tid = threadIdx.x;
  const int lane = tid & 63;
  const int dt = tid >> 6;
  const int m = lane & 15;
  const int g = lane >> 4;
  const int segbase = seg * SEG_TOK;

  __shared__ __align__(16) unsigned short rq[32][68];
  __shared__ __align__(16) unsigned short rk[32][68];
  __shared__ __align__(16) unsigned short rv[32][68];
  __shared__ __align__(16) _Float16 qs[16][72];
  __shared__ __align__(16) _Float16 ks[16][72];
  __shared__ __align__(16) _Float16 kts[64][20];
  __shared__ __align__(16) _Float16 vts[64][20];

  v4f Wf[4];
#pragma unroll
  for (int kt = 0; kt < 4; kt++) Wf[kt] = (v4f){0.f, 0.f, 0.f, 0.f};

  const int srow = tid >> 4;
  const int scol = (tid & 15) * 4;
  const size_t gcol = (size_t)h * 64 + scol;

  float wq[4][4], wk[4][4], wv[4][4];
#pragma unroll
  for (int e = 0; e < 4; e++) {
    const float4 a = *(const float4*)(CWq + (gcol + e) * 4);
    const float4 bw = *(const float4*)(CWk + (gcol + e) * 4);
    const float4 cw = *(const float4*)(CWv + (gcol + e) * 4);
    wq[e][0] = a.x; wq[e][1] = a.y; wq[e][2] = a.z; wq[e][3] = a.w;
    wk[e][0] = bw.x; wk[e][1] = bw.y; wk[e][2] = bw.z; wk[e][3] = bw.w;
    wv[e][0] = cw.x; wv[e][1] = cw.y; wv[e][2] = cw.z; wv[e][3] = cw.w;
  }

  if (tid < 48) {
    const int j = tid >> 4;
    const int sc = (tid & 15) * 4;
    const size_t so = ((size_t)((b * NSEG + seg) * 3 + j)) * DIM + h * 64 + sc;
    const int slot = (29 + j);
    *(uint2*)&rq[slot][sc] = *(const uint2*)(sQ + so);
    *(uint2*)&rk[slot][sc] = *(const uint2*)(sK + so);
    *(uint2*)&rv[slot][sc] = *(const uint2*)(sV + so);
  }

  size_t gb = ((size_t)(b * L + segbase + srow)) * DIM + gcol;
  uint2 qg = *(const uint2*)(Qr + gb);
  uint2 kg = *(const uint2*)(Kr + gb);
  uint2 vg = *(const uint2*)(Vr + gb);

  for (int c = 0; c < SEG_CHUNKS; c++) {
    const int t = segbase + c * 16 + srow;
    __syncthreads();  // (A)
    *(uint2*)&rq[t & 31][scol] = qg;
    *(uint2*)&rk[t & 31][scol] = kg;
    *(uint2*)&rv[t & 31][scol] = vg;
    const int cn = (c + 1 < SEG_CHUNKS) ? c + 1 : c;
    const size_t gbn = ((size_t)(b * L + segbase + cn * 16 + srow)) * DIM + gcol;
    const uint2 qn = *(const uint2*)(Qr + gbn);
    const uint2 kn = *(const uint2*)(Kr + gbn);
    const uint2 vn = *(const uint2*)(Vr + gbn);
    __syncthreads();  // (B)

    float sq[4], sk[4], sv[4];
    {
      float q0[4], q1[4], q2[4], q3[4];
      float k0[4], k1[4], k2[4], k3[4];
      float v0[4], v1[4], v2[4], v3[4];
      u2_unpack(qg, q0);
      u2_unpack(kg, k0);
      u2_unpack(vg, v0);
      u2_unpack(*(const uint2*)&rq[(t - 1) & 31][scol], q1);
      u2_unpack(*(const uint2*)&rk[(t - 1) & 31][scol], k1);
      u2_unpack(*(const uint2*)&rv[(t - 1) & 31][scol], v1);
      u2_unpack(*(const uint2*)&rq[(t - 2) & 31][scol], q2);
      u2_unpack(*(const uint2*)&rk[(t - 2) & 31][scol], k2);
      u2_unpack(*(const uint2*)&rv[(t - 2) & 31][scol], v2);
      u2_unpack(*(const uint2*)&rq[(t - 3) & 31][scol], q3);
      u2_unpack(*(const uint2*)&rk[(t - 3) & 31][scol], k3);
      u2_unpack(*(const uint2*)&rv[(t - 3) & 31][scol], v3);
#pragma unroll
      for (int e = 0; e < 4; e++) {
        const float yq = q0[e] + wq[e][0] * q3[e] + wq[e][1] * q2[e] + wq[e][2] * q1[e] + wq[e][3] * q0[e];
        const float yk = k0[e] + wk[e][0] * k3[e] + wk[e][1] * k2[e] + wk[e][2] * k1[e] + wk[e][3] * k0[e];
        const float yv = v0[e] + wv[e][0] * v3[e] + wv[e][1] * v2[e] + wv[e][2] * v1[e] + wv[e][3] * v0[e];
        sq[e] = yq / (1.f + __expf(-yq));
        sk[e] = yk / (1.f + __expf(-yk));
        sv[e] = yv / (1.f + __expf(-yv));
      }
    }
    float ssq = sq[0] * sq[0] + sq[1] * sq[1] + sq[2] * sq[2] + sq[3] * sq[3];
    float ssk = sk[0] * sk[0] + sk[1] * sk[1] + sk[2] * sk[2] + sk[3] * sk[3];
#pragma unroll
    for (int off = 8; off >= 1; off >>= 1) {
      ssq += __shfl_xor(ssq, off, 16);
      ssk += __shfl_xor(ssk, off, 16);
    }
    const float scq = rsqrtf(ssq + 1e-12f);
    const float sck = rsqrtf(ssk + 1e-12f);

    const v4h qh = {(_Float16)(sq[0] * scq), (_Float16)(sq[1] * scq),
                    (_Float16)(sq[2] * scq), (_Float16)(sq[3] * scq)};
    const v4h kh = {(_Float16)(sk[0] * sck), (_Float16)(sk[1] * sck),
                    (_Float16)(sk[2] * sck), (_Float16)(sk[3] * sck)};
    *(v4h*)&qs[srow][scol] = qh;
    *(v4h*)&ks[srow][scol] = kh;
    kts[scol + 0][srow] = kh[0]; kts[scol + 1][srow] = kh[1];
    kts[scol + 2][srow] = kh[2]; kts[scol + 3][srow] = kh[3];
    vts[scol + 0][srow] = (_Float16)sv[0]; vts[scol + 1][srow] = (_Float16)sv[1];
    vts[scol + 2][srow] = (_Float16)sv[2]; vts[scol + 3][srow] = (_Float16)sv[3];

    uint2 qp;
    __builtin_memcpy(&qp, &qh, 8);
    *(uint2*)(Qr + gb) = qp;  // qc (f16) for phase C

    __syncthreads();  // (C)

    v4h qf[4], kf[4], ktf[4];
#pragma unroll
    for (int kt = 0; kt < 4; kt++) {
      qf[kt] = *(const v4h*)&qs[m][kt * 16 + 4 * g];
      kf[kt] = *(const v4h*)&ks[m][kt * 16 + 4 * g];
      ktf[kt] = *(const v4h*)&kts[kt * 16 + m][4 * g];
    }
    const v4h vf = *(const v4h*)&vts[dt * 16 + m][4 * g];

    v4f kq = {0.f, 0.f, 0.f, 0.f};
#pragma unroll
    for (int kt = 0; kt < 4; kt++) kq = MFMA_F16_16x16x16(kf[kt], qf[kt], kq);

    v4h kqA;
#pragma unroll
    for (int e = 0; e < 4; e++)
      kqA[e] = (4 * g + e <= m) ? (_Float16)kq[e] : (_Float16)0.f;

    v4f of = {0.f, 0.f, 0.f, 0.f};
    of = MFMA_F16_16x16x16(kqA, vf, of);
#pragma unroll
    for (int kt = 0; kt < 4; kt++) {
      v4h Wh;
#pragma unroll
      for (int e = 0; e < 4; e++) Wh[e] = (_Float16)Wf[kt][e];
      of = MFMA_F16_16x16x16(qf[kt], Wh, of);
    }
#pragma unroll
    for (int kt = 0; kt < 4; kt++) Wf[kt] = MFMA_F16_16x16x16(ktf[kt], vf, Wf[kt]);

    const size_t ob = ((size_t)(b * L + segbase + c * 16 + 4 * g)) * DIM + h * 64 + dt * 16 + m;
#pragma unroll
    for (int e = 0; e < 4; e++) Vr[ob + (size_t)e * DIM] = f2h_us(of[e]);

    qg = qn; kg = kn; vg = vn; gb = gbn;
  }

  float* Dp = D + ((size_t)((b * 16 + h) * NSEG + seg)) * 4096;
#pragma unroll
  for (int kt = 0; kt < 4; kt++)
#pragma unroll
    for (int e = 0; e < 4; e++)
      Dp[(kt * 16 + 4 * g + e) * 64 + dt * 16 + m] = Wf[kt][e];
}

// ---------------------------------------------------------------------------
// Phase B: exclusive prefix over segments, seeded with W0. grid 64, block 256.
// ---------------------------------------------------------------------------
__global__ __launch_bounds__(256) void prefix_D(float* __restrict__ D,
                                                const float* __restrict__ W0) {
  const int bh = blockIdx.x;
  const int h = bh & 15;
  const int tid = threadIdx.x;
  float p[16];
#pragma unroll
  for (int i = 0; i < 16; i++) p[i] = W0[(size_t)h * 4096 + tid + i * 256];
  for (int s = 0; s < NSEG; s++) {
    float* Dp = D + ((size_t)bh * NSEG + s) * 4096;
#pragma unroll
    for (int i = 0; i < 16; i++) {
      const float t = Dp[tid + i * 256];
      Dp[tid + i * 256] = p[i];
      p[i] += t;
    }
  }
}

// ---------------------------------------------------------------------------
// Phase C: o += qc @ P_seg. grid 1024; block 256.
// ---------------------------------------------------------------------------
__global__ __launch_bounds__(256) void apply_corr(const unsigned short* __restrict__ Qc,
                                                  const float* __restrict__ P,
                                                  unsigned short* __restrict__ Op) {
  const int seg = blockIdx.x & 15;
  const int h = (blockIdx.x >> 4) & 15;
  const int b = blockIdx.x >> 8;
  const int tid = threadIdx.x;
  const int lane = tid & 63;
  const int dt = tid >> 6;
  const int m = lane & 15;
  const int g = lane >> 4;

  __shared__ __align__(16) _Float16 Pt[64][72];
  __shared__ __align__(16) _Float16 qt[16][72];

  const float* Pp = P + ((size_t)((b * 16 + h) * NSEG + seg)) * 4096;
#pragma unroll
  for (int i = 0; i < 16; i++) {
    const int el = tid + i * 256;
    Pt[el & 63][el >> 6] = (_Float16)Pp[el];
  }
  __syncthreads();

  v4h pb[4];
#pragma unroll
  for (int kt = 0; kt < 4; kt++) pb[kt] = *(const v4h*)&Pt[dt * 16 + m][kt * 16 + 4 * g];

  const int srow = tid >> 4;
  const int scol = (tid & 15) * 4;
  for (int rt = 0; rt < 8; rt++) {
    const size_t gb = ((size_t)(b * L + seg * SEG_TOK + rt * 16 + srow)) * DIM + h * 64 + scol;
    const uint2 qg = *(const uint2*)(Qc + gb);
    __syncthreads();
    *(uint2*)&qt[srow][scol] = qg;
    __syncthreads();
    v4h qf[4];
#pragma unroll
    for (int kt = 0; kt < 4; kt++) qf[kt] = *(const v4h*)&qt[m][kt * 16 + 4 * g];
    v4f corr = {0.f, 0.f, 0.f, 0.f};
#pragma unroll
    for (int kt = 0; kt < 4; kt++) corr = MFMA_F16_16x16x16(qf[kt], pb[kt], corr);
    const size_t ob = ((size_t)(b * L + seg * SEG_TOK + rt * 16 + 4 * g)) * DIM + h * 64 + dt * 16 + m;
#pragma unroll
    for (int e = 0; e < 4; e++) {
      const float v = h2f_us(Op[ob + (size_t)e * DIM]) + corr[e];
      Op[ob + (size_t)e * DIM] = f2h_us(v);
    }
  }
}

// ---------------------------------------------------------------------------
// LayerNorm over dk=64 per head + gate multiply. O f16 in -> bf16 out
// (in place); gate bf16; gamma/beta fp32.
// ---------------------------------------------------------------------------
__global__ __launch_bounds__(256) void ln_gate(unsigned short* __restrict__ Ob,
                                               const unsigned short* __restrict__ G,
                                               const float* __restrict__ gamma,
                                               const float* __restrict__ beta) {
  const int r = blockIdx.x;
  const int tid = threadIdx.x;
  const int c = tid * 4;
  float o[4];
  h4_unpack(*(const uint2*)(Ob + (size_t)r * DIM + c), o);
  float sum = o[0] + o[1] + o[2] + o[3];
#pragma unroll
  for (int off = 8; off >= 1; off >>= 1) sum += __shfl_xor(sum, off, 16);
  const float mu = sum * (1.f / 64.f);
  float d[4];
  float vs = 0.f;
#pragma unroll
  for (int e = 0; e < 4; e++) { d[e] = o[e] - mu; vs += d[e] * d[e]; }
#pragma unroll
  for (int off = 8; off >= 1; off >>= 1) vs += __shfl_xor(vs, off, 16);
  const float rstd = rsqrtf(vs * (1.f / 64.f) + 1e-5f);
  const int dl = c & 63;
  const float4 gm = *(const float4*)(gamma + dl);
  const float4 bt = *(const float4*)(beta + dl);
  float gt[4];
  u2_unpack(*(const uint2*)(G + (size_t)r * DIM + c), gt);
  float outv[4];
  outv[0] = (d[0] * rstd * gm.x + bt.x) * gt[0];
  outv[1] = (d[1] * rstd * gm.y + bt.y) * gt[1];
  outv[2] = (d[2] * rstd * gm.z + bt.z) * gt[2];
  outv[3] = (d[3] * rstd * gm.w + bt.w) * gt[3];
  uint2 u;
  u.x = (unsigned int)f2bf(outv[0]) | ((unsigned int)f2bf(outv[1]) << 16);
  u.y = (unsigned int)f2bf(outv[2]) | ((unsigned int)f2bf(outv[3]) << 16);
  *(uint2*)(Ob + (size_t)r * DIM + c) = u;
}

// ---------------------------------------------------------------------------
// ws (48 MB): sA=qlin->qc(f16)->Wobf, sB=klin->gate, sC=vlin->o->o_ln
// d_out (33.5 MB): Hbf [0,16.78M) -> D overlays after q/k/v GEMMs;
//                  Wbf x4 [16.78M, +8.39M); side [+8.39M, +1.18M).
// Final fp32 GEMM overwrites all of d_out last.
// ---------------------------------------------------------------------------
extern "C" void kernel_launch(void* const* d_in, const int* in_sizes, int n_in,
                              void* d_out, int out_size, void* d_ws, size_t ws_size,
                              hipStream_t stream) {
  const float* H  = (const float*)d_in[0];
  const float* Wq = (const float*)d_in[1];
  const float* Wk = (const float*)d_in[2];
  const float* Wv = (const float*)d_in[3];
  const float* cq = (const float*)d_in[4];
  const float* ck = (const float*)d_in[5];
  const float* cv = (const float*)d_in[6];
  const float* W0 = (const float*)d_in[7];
  const float* gamma = (const float*)d_in[8];
  const float* beta  = (const float*)d_in[9];
  const float* Wg = (const float*)d_in[10];
  const float* Wo = (const float*)d_in[11];

  const size_t SZ = (size_t)ROWS * DIM;   // 8M elements
  const size_t WSZ = (size_t)DIM * DIM;   // 1M elements
  unsigned short* sA = (unsigned short*)d_ws;
  unsigned short* sB = sA + SZ;
  unsigned short* sC = sB + SZ;

  unsigned short* Hbf = (unsigned short*)d_out;        // dies before D
  unsigned short* Wbf = Hbf + SZ;                      // Wq,Wk,Wv,Wg bf16
  unsigned short* side = Wbf + 4 * WSZ;
  unsigned short* sideQ = side;
  unsigned short* sideK = side + (size_t)192 * DIM;
  unsigned short* sideV = side + (size_t)384 * DIM;
  float* D = (float*)d_out;                            // overlays Hbf

  const dim3 gg(DIM / 128, ROWS / 128);
  cvt_f2b<<<SZ / 1024, 256, 0, stream>>>(H, Hbf);
  cvt_w4<<<4096, 256, 0, stream>>>(Wq, Wk, Wv, Wg, Wbf);

  gemm_t<1, 1, 0><<<gg, 256, 0, stream>>>(Hbf, Wbf + 0 * WSZ, sA);  // qlin
  gemm_t<1, 1, 0><<<gg, 256, 0, stream>>>(Hbf, Wbf + 1 * WSZ, sB);  // klin
  gemm_t<1, 1, 0><<<gg, 256, 0, stream>>>(Hbf, Wbf + 2 * WSZ, sC);  // vlin

  copy_side<<<192, 256, 0, stream>>>(sA, sB, sC, sideQ, sideK, sideV);

  scan_seg<<<1024, 256, 0, stream>>>(sA, sB, sC, sideQ, sideK, sideV,
                                     cq, ck, cv, D);

  gemm_t<0, 1, 0><<<gg, 256, 0, stream>>>(H, Wbf + 3 * WSZ, sB);  // gate

  prefix_D<<<64, 256, 0, stream>>>(D, W0);

  apply_corr<<<1024, 256, 0, stream>>>(sA, D, sC);

  ln_gate<<<ROWS, 256, 0, stream>>>(sC, sB, gamma, beta);

  cvt_f2b<<<WSZ / 1024, 256, 0, stream>>>(Wo, sA);  // Wobf -> sA (qc dead)

  gemm_t<1, 1, 1><<<gg, 256, 0, stream>>>(sC, sA, d_out);  // fp32 output
}

// Round 8
// 323.688 us; speedup vs baseline: 1.7400x; 1.0639x over previous
//
#include <hip/hip_runtime.h>

#define L 2048
#define DIM 1024
#define ROWS 8192     // b*l
#define NSEG 16       // segments per sequence
#define SEG_CHUNKS 8  // chunks per segment
#define SEG_TOK 128   // tokens per segment

typedef __attribute__((ext_vector_type(4))) _Float16 v4h;
typedef __attribute__((ext_vector_type(4))) float v4f;
typedef __attribute__((ext_vector_type(8))) short v8s;

#if defined(__HIP_DEVICE_COMPILE__)
#define MFMA_F16_16x16x16(a, b, c) __builtin_amdgcn_mfma_f32_16x16x16f16((a), (b), (c), 0, 0, 0)
#define MFMA_BF16_16x16x32(a, b, c) __builtin_amdgcn_mfma_f32_16x16x32_bf16((a), (b), (c), 0, 0, 0)
#else
#define MFMA_F16_16x16x16(a, b, c) (c)
#define MFMA_BF16_16x16x32(a, b, c) (c)
#endif

// async global->LDS, 16B per lane; LDS dest = wave-uniform base + lane*16
__device__ inline void gld16(const unsigned short* g, unsigned short* l) {
#if defined(__HIP_DEVICE_COMPILE__)
  __builtin_amdgcn_global_load_lds(
      (__attribute__((address_space(1))) void*)g,
      (__attribute__((address_space(3))) void*)l, 16, 0, 0);
#endif
}

__device__ inline unsigned short f2bf(float f) {
  unsigned int u = __float_as_uint(f);
  unsigned int r = (u + 0x7fffu + ((u >> 16) & 1u)) >> 16;
  return (unsigned short)r;
}
__device__ inline void u2_unpack(const uint2 u, float* f) {  // bf16 x4
  f[0] = __uint_as_float((u.x & 0xffffu) << 16);
  f[1] = __uint_as_float(u.x & 0xffff0000u);
  f[2] = __uint_as_float((u.y & 0xffffu) << 16);
  f[3] = __uint_as_float(u.y & 0xffff0000u);
}
__device__ inline uint4 pack8(const float4 a, const float4 b) {
  uint4 u;
  u.x = (unsigned int)f2bf(a.x) | ((unsigned int)f2bf(a.y) << 16);
  u.y = (unsigned int)f2bf(a.z) | ((unsigned int)f2bf(a.w) << 16);
  u.z = (unsigned int)f2bf(b.x) | ((unsigned int)f2bf(b.y) << 16);
  u.w = (unsigned int)f2bf(b.z) | ((unsigned int)f2bf(b.w) << 16);
  return u;
}
__device__ inline unsigned short f2h_us(float f) {
  _Float16 h = (_Float16)f;
  unsigned short u;
  __builtin_memcpy(&u, &h, 2);
  return u;
}
__device__ inline float h2f_us(unsigned short u) {
  _Float16 h;
  __builtin_memcpy(&h, &u, 2);
  return (float)h;
}
__device__ inline void h4_unpack(const uint2 u, float* f) {  // f16 x4
  f[0] = h2f_us((unsigned short)(u.x & 0xffffu));
  f[1] = h2f_us((unsigned short)(u.x >> 16));
  f[2] = h2f_us((unsigned short)(u.y & 0xffffu));
  f[3] = h2f_us((unsigned short)(u.y >> 16));
}

// ---------------------------------------------------------------------------
// fp32 -> bf16 converters
// ---------------------------------------------------------------------------
__global__ __launch_bounds__(256) void cvt_f2b(const float* __restrict__ s,
                                               unsigned short* __restrict__ d) {
  const int i = blockIdx.x * 256 + threadIdx.x;
  const float4 v = ((const float4*)s)[i];
  uint2 u;
  u.x = (unsigned int)f2bf(v.x) | ((unsigned int)f2bf(v.y) << 16);
  u.y = (unsigned int)f2bf(v.z) | ((unsigned int)f2bf(v.w) << 16);
  ((uint2*)d)[i] = u;
}

__global__ __launch_bounds__(256) void cvt_w4(const float* __restrict__ w0,
                                              const float* __restrict__ w1,
                                              const float* __restrict__ w2,
                                              const float* __restrict__ w3,
                                              unsigned short* __restrict__ dst) {
  const int t = blockIdx.x >> 10;
  const int i = (blockIdx.x & 1023) * 256 + threadIdx.x;
  const float* s = (t == 0) ? w0 : (t == 1) ? w1 : (t == 2) ? w2 : w3;
  const float4 v = ((const float4*)s)[i];
  uint2 u;
  u.x = (unsigned int)f2bf(v.x) | ((unsigned int)f2bf(v.y) << 16);
  u.y = (unsigned int)f2bf(v.z) | ((unsigned int)f2bf(v.w) << 16);
  ((uint2*)(dst + (size_t)t * DIM * DIM))[i] = u;
}

// ---------------------------------------------------------------------------
// m97-style GEMM: C[M,N] = A[M,K] @ B[N,K]^T, bf16 in, BK=64, 128x128 tile,
// global_load_lds width-16 staging, XOR-swizzled LDS (chunk ^= row&7 -> lane-
// contiguous staging AND 2-way-max ds_read_b128 conflicts). Output buffer
// selected by bn>>10 (fused multi-weight GEMM); OUTF32 for final fp32 out.
// ---------------------------------------------------------------------------
template <int OUTF32>
__global__ __launch_bounds__(256) void gemm_a(const unsigned short* __restrict__ A,
                                              const unsigned short* __restrict__ B,
                                              void* __restrict__ Cv) {
  __shared__ __align__(16) unsigned short As[128 * 64];
  __shared__ __align__(16) unsigned short Bs[128 * 64];
  const int tid = threadIdx.x;
  const int bm = blockIdx.y * 128;
  const int bn = blockIdx.x * 128;
  const int wave = tid >> 6;
  const int lane = tid & 63;
  const int m16 = lane & 15;
  const int g = lane >> 4;
  const int wm = (wave >> 1) * 64;
  const int wn = (wave & 1) * 64;
  const int srow8 = lane >> 3;  // row within 8-row staging group
  const int schk = lane & 7;    // LDS chunk this lane fills

  v4f acc[4][4];
#pragma unroll
  for (int i = 0; i < 4; i++)
#pragma unroll
    for (int j = 0; j < 4; j++) acc[i][j] = (v4f){0.f, 0.f, 0.f, 0.f};

  for (int kt = 0; kt < DIM; kt += 64) {
    __syncthreads();  // all waves done reading previous tile
#pragma unroll
    for (int j = 0; j < 4; j++) {
      const int r = wave * 32 + j * 8 + srow8;  // 0..127
      const int cg = schk ^ (r & 7);            // global chunk for this lane
      gld16(A + (size_t)(bm + r) * DIM + kt + cg * 8, &As[(wave * 32 + j * 8) * 64]);
      gld16(B + (size_t)(bn + r) * DIM + kt + cg * 8, &Bs[(wave * 32 + j * 8) * 64]);
    }
    __syncthreads();  // drains vmcnt -> LDS visible
#pragma unroll
    for (int kh = 0; kh < 2; kh++) {
      v8s af[4], bf[4];
#pragma unroll
      for (int i = 0; i < 4; i++) {
        const int r = wm + i * 16 + m16;
        af[i] = *(const v8s*)&As[r * 64 + (((kh * 4 + g) ^ (r & 7)) * 8)];
      }
#pragma unroll
      for (int j = 0; j < 4; j++) {
        const int r = wn + j * 16 + m16;
        bf[j] = *(const v8s*)&Bs[r * 64 + (((kh * 4 + g) ^ (r & 7)) * 8)];
      }
#pragma unroll
      for (int i = 0; i < 4; i++)
#pragma unroll
        for (int j = 0; j < 4; j++) acc[i][j] = MFMA_BF16_16x16x32(af[i], bf[j], acc[i][j]);
    }
  }

  const int t = bn >> 10;     // which output buffer (fused QKV)
  const int cb = bn & 1023;   // column within that buffer
#pragma unroll
  for (int i = 0; i < 4; i++)
#pragma unroll
    for (int e = 0; e < 4; e++) {
      const size_t row = (size_t)(bm + wm + i * 16 + 4 * g + e);
#pragma unroll
      for (int j = 0; j < 4; j++) {
        const size_t idx = row * DIM + cb + wn + j * 16 + m16;
        if (OUTF32)
          ((float*)Cv)[idx] = acc[i][j][e];
        else
          ((unsigned short*)Cv)[(size_t)t * ((size_t)ROWS * DIM) + idx] = f2bf(acc[i][j][e]);
      }
    }
}

// ---------------------------------------------------------------------------
// Legacy GEMM for the gate (A = fp32 H; Hbf is dead by gate time since D
// overlays it). bf16 MFMA, pack in staging.
// ---------------------------------------------------------------------------
__global__ __launch_bounds__(256) void gemm_gate(const float* __restrict__ Af,
                                                 const unsigned short* __restrict__ Bf,
                                                 unsigned short* __restrict__ C) {
  __shared__ __align__(16) unsigned short As[128][40];
  __shared__ __align__(16) unsigned short Bs[128][40];
  const int tid = threadIdx.x;
  const int bm = blockIdx.y * 128;
  const int bn = blockIdx.x * 128;
  const int wave = tid >> 6;
  const int lane = tid & 63;
  const int m16 = lane & 15;
  const int g = lane >> 4;
  const int wm = (wave >> 1) * 64;
  const int wn = (wave & 1) * 64;
  const int lr = tid >> 2;
  const int lc = (tid & 3) * 8;

  v4f acc[4][4];
#pragma unroll
  for (int i = 0; i < 4; i++)
#pragma unroll
    for (int j = 0; j < 4; j++) acc[i][j] = (v4f){0.f, 0.f, 0.f, 0.f};

  auto loadAB = [&](int kt, uint4& a0, uint4& a1, uint4& b0, uint4& b1) {
    const float* p0 = Af + (size_t)(bm + lr) * DIM + lc + kt;
    const float* p1 = Af + (size_t)(bm + 64 + lr) * DIM + lc + kt;
    a0 = pack8(*(const float4*)p0, *(const float4*)(p0 + 4));
    a1 = pack8(*(const float4*)p1, *(const float4*)(p1 + 4));
    b0 = *(const uint4*)(Bf + (size_t)(bn + lr) * DIM + lc + kt);
    b1 = *(const uint4*)(Bf + (size_t)(bn + 64 + lr) * DIM + lc + kt);
  };

  uint4 a0, a1, b0, b1;
  loadAB(0, a0, a1, b0, b1);

  for (int kt = 0; kt < DIM; kt += 32) {
    __syncthreads();
    *(uint4*)&As[lr][lc] = a0;
    *(uint4*)&As[64 + lr][lc] = a1;
    *(uint4*)&Bs[lr][lc] = b0;
    *(uint4*)&Bs[64 + lr][lc] = b1;
    __syncthreads();
    if (kt + 32 < DIM) loadAB(kt + 32, a0, a1, b0, b1);
    v8s af[4], bf[4];
#pragma unroll
    for (int i = 0; i < 4; i++) af[i] = *(const v8s*)&As[wm + i * 16 + m16][g * 8];
#pragma unroll
    for (int j = 0; j < 4; j++) bf[j] = *(const v8s*)&Bs[wn + j * 16 + m16][g * 8];
#pragma unroll
    for (int i = 0; i < 4; i++)
#pragma unroll
      for (int j = 0; j < 4; j++) acc[i][j] = MFMA_BF16_16x16x32(af[i], bf[j], acc[i][j]);
  }

#pragma unroll
  for (int i = 0; i < 4; i++)
#pragma unroll
    for (int e = 0; e < 4; e++) {
      const size_t row = (size_t)(bm + wm + i * 16 + 4 * g + e);
#pragma unroll
      for (int j = 0; j < 4; j++)
        C[row * DIM + bn + wn + j * 16 + m16] = f2bf(acc[i][j][e]);
    }
}

// ---------------------------------------------------------------------------
// Copy 3 pre-segment boundary rows of raw q/k/v linears to a side buffer.
// ---------------------------------------------------------------------------
__global__ __launch_bounds__(256) void copy_side(const unsigned short* __restrict__ Q,
                                                 const unsigned short* __restrict__ K,
                                                 const unsigned short* __restrict__ V,
                                                 unsigned short* __restrict__ sQ,
                                                 unsigned short* __restrict__ sK,
                                                 unsigned short* __restrict__ sV) {
  const int idx = blockIdx.x;
  const int j = idx % 3;
  const int bs = idx / 3;
  const int seg = bs & 15;
  const int b = bs >> 4;
  const int ch = threadIdx.x * 4;
  const size_t so = ((size_t)(bs * 3 + j)) * DIM + ch;
  if (seg == 0) {
    const uint2 z = {0u, 0u};
    *(uint2*)(sQ + so) = z;
    *(uint2*)(sK + so) = z;
    *(uint2*)(sV + so) = z;
  } else {
    const size_t go = ((size_t)(b * L + seg * SEG_TOK - 3 + j)) * DIM + ch;
    *(uint2*)(sQ + so) = *(const uint2*)(Q + go);
    *(uint2*)(sK + so) = *(const uint2*)(K + go);
    *(uint2*)(sV + so) = *(const uint2*)(V + go);
  }
}

// ---------------------------------------------------------------------------
// Phase A: segmented fused conv+SiLU(+L2norm) + local Titans scan from W=0.
// ---------------------------------------------------------------------------
__global__ __launch_bounds__(256) void scan_seg(unsigned short* __restrict__ Qr,
                                                const unsigned short* __restrict__ Kr,
                                                unsigned short* __restrict__ Vr,
                                                const unsigned short* __restrict__ sQ,
                                                const unsigned short* __restrict__ sK,
                                                const unsigned short* __restrict__ sV,
                                                const float* __restrict__ CWq,
                                                const float* __restrict__ CWk,
                                                const float* __restrict__ CWv,
                                                float* __restrict__ D) {
  const int seg = blockIdx.x & 15;
  const int h = (blockIdx.x >> 4) & 15;
  const int b = blockIdx.x >> 8;
  const int tid = threadIdx.x;
  const int lane = tid & 63;
  const int dt = tid >> 6;
  const int m = lane & 15;
  const int g = lane >> 4;
  const int segbase = seg * SEG_TOK;

  __shared__ __align__(16) unsigned short rq[32][68];
  __shared__ __align__(16) unsigned short rk[32][68];
  __shared__ __align__(16) unsigned short rv[32][68];
  __shared__ __align__(16) _Float16 qs[16][72];
  __shared__ __align__(16) _Float16 ks[16][72];
  __shared__ __align__(16) _Float16 kts[64][20];
  __shared__ __align__(16) _Float16 vts[64][20];

  v4f Wf[4];
#pragma unroll
  for (int kt = 0; kt < 4; kt++) Wf[kt] = (v4f){0.f, 0.f, 0.f, 0.f};

  const int srow = tid >> 4;
  const int scol = (tid & 15) * 4;
  const size_t gcol = (size_t)h * 64 + scol;

  float wq[4][4], wk[4][4], wv[4][4];
#pragma unroll
  for (int e = 0; e < 4; e++) {
    const float4 a = *(const float4*)(CWq + (gcol + e) * 4);
    const float4 bw = *(const float4*)(CWk + (gcol + e) * 4);
    const float4 cw = *(const float4*)(CWv + (gcol + e) * 4);
    wq[e][0] = a.x; wq[e][1] = a.y; wq[e][2] = a.z; wq[e][3] = a.w;
    wk[e][0] = bw.x; wk[e][1] = bw.y; wk[e][2] = bw.z; wk[e][3] = bw.w;
    wv[e][0] = cw.x; wv[e][1] = cw.y; wv[e][2] = cw.z; wv[e][3] = cw.w;
  }

  if (tid < 48) {
    const int j = tid >> 4;
    const int sc = (tid & 15) * 4;
    const size_t so = ((size_t)((b * NSEG + seg) * 3 + j)) * DIM + h * 64 + sc;
    const int slot = (29 + j);
    *(uint2*)&rq[slot][sc] = *(const uint2*)(sQ + so);
    *(uint2*)&rk[slot][sc] = *(const uint2*)(sK + so);
    *(uint2*)&rv[slot][sc] = *(const uint2*)(sV + so);
  }

  size_t gb = ((size_t)(b * L + segbase + srow)) * DIM + gcol;
  uint2 qg = *(const uint2*)(Qr + gb);
  uint2 kg = *(const uint2*)(Kr + gb);
  uint2 vg = *(const uint2*)(Vr + gb);

  for (int c = 0; c < SEG_CHUNKS; c++) {
    const int t = segbase + c * 16 + srow;
    __syncthreads();
    *(uint2*)&rq[t & 31][scol] = qg;
    *(uint2*)&rk[t & 31][scol] = kg;
    *(uint2*)&rv[t & 31][scol] = vg;
    const int cn = (c + 1 < SEG_CHUNKS) ? c + 1 : c;
    const size_t gbn = ((size_t)(b * L + segbase + cn * 16 + srow)) * DIM + gcol;
    const uint2 qn = *(const uint2*)(Qr + gbn);
    const uint2 kn = *(const uint2*)(Kr + gbn);
    const uint2 vn = *(const uint2*)(Vr + gbn);
    __syncthreads();

    float sq[4], sk[4], sv[4];
    {
      float q0[4], q1[4], q2[4], q3[4];
      float k0[4], k1[4], k2[4], k3[4];
      float v0[4], v1[4], v2[4], v3[4];
      u2_unpack(qg, q0);
      u2_unpack(kg, k0);
      u2_unpack(vg, v0);
      u2_unpack(*(const uint2*)&rq[(t - 1) & 31][scol], q1);
      u2_unpack(*(const uint2*)&rk[(t - 1) & 31][scol], k1);
      u2_unpack(*(const uint2*)&rv[(t - 1) & 31][scol], v1);
      u2_unpack(*(const uint2*)&rq[(t - 2) & 31][scol], q2);
      u2_unpack(*(const uint2*)&rk[(t - 2) & 31][scol], k2);
      u2_unpack(*(const uint2*)&rv[(t - 2) & 31][scol], v2);
      u2_unpack(*(const uint2*)&rq[(t - 3) & 31][scol], q3);
      u2_unpack(*(const uint2*)&rk[(t - 3) & 31][scol], k3);
      u2_unpack(*(const uint2*)&rv[(t - 3) & 31][scol], v3);
#pragma unroll
      for (int e = 0; e < 4; e++) {
        const float yq = q0[e] + wq[e][0] * q3[e] + wq[e][1] * q2[e] + wq[e][2] * q1[e] + wq[e][3] * q0[e];
        const float yk = k0[e] + wk[e][0] * k3[e] + wk[e][1] * k2[e] + wk[e][2] * k1[e] + wk[e][3] * k0[e];
        const float yv = v0[e] + wv[e][0] * v3[e] + wv[e][1] * v2[e] + wv[e][2] * v1[e] + wv[e][3] * v0[e];
        sq[e] = yq / (1.f + __expf(-yq));
        sk[e] = yk / (1.f + __expf(-yk));
        sv[e] = yv / (1.f + __expf(-yv));
      }
    }
    float ssq = sq[0] * sq[0] + sq[1] * sq[1] + sq[2] * sq[2] + sq[3] * sq[3];
    float ssk = sk[0] * sk[0] + sk[1] * sk[1] + sk[2] * sk[2] + sk[3] * sk[3];
#pragma unroll
    for (int off = 8; off >= 1; off >>= 1) {
      ssq += __shfl_xor(ssq, off, 16);
      ssk += __shfl_xor(ssk, off, 16);
    }
    const float scq = rsqrtf(ssq + 1e-12f);
    const float sck = rsqrtf(ssk + 1e-12f);

    const v4h qh = {(_Float16)(sq[0] * scq), (_Float16)(sq[1] * scq),
                    (_Float16)(sq[2] * scq), (_Float16)(sq[3] * scq)};
    const v4h kh = {(_Float16)(sk[0] * sck), (_Float16)(sk[1] * sck),
                    (_Float16)(sk[2] * sck), (_Float16)(sk[3] * sck)};
    *(v4h*)&qs[srow][scol] = qh;
    *(v4h*)&ks[srow][scol] = kh;
    kts[scol + 0][srow] = kh[0]; kts[scol + 1][srow] = kh[1];
    kts[scol + 2][srow] = kh[2]; kts[scol + 3][srow] = kh[3];
    vts[scol + 0][srow] = (_Float16)sv[0]; vts[scol + 1][srow] = (_Float16)sv[1];
    vts[scol + 2][srow] = (_Float16)sv[2]; vts[scol + 3][srow] = (_Float16)sv[3];

    uint2 qp;
    __builtin_memcpy(&qp, &qh, 8);
    *(uint2*)(Qr + gb) = qp;  // qc (f16) for phase C

    __syncthreads();

    v4h qf[4], kf[4], ktf[4];
#pragma unroll
    for (int kt = 0; kt < 4; kt++) {
      qf[kt] = *(const v4h*)&qs[m][kt * 16 + 4 * g];
      kf[kt] = *(const v4h*)&ks[m][kt * 16 + 4 * g];
      ktf[kt] = *(const v4h*)&kts[kt * 16 + m][4 * g];
    }
    const v4h vf = *(const v4h*)&vts[dt * 16 + m][4 * g];

    v4f kq = {0.f, 0.f, 0.f, 0.f};
#pragma unroll
    for (int kt = 0; kt < 4; kt++) kq = MFMA_F16_16x16x16(kf[kt], qf[kt], kq);

    v4h kqA;
#pragma unroll
    for (int e = 0; e < 4; e++)
      kqA[e] = (4 * g + e <= m) ? (_Float16)kq[e] : (_Float16)0.f;

    v4f of = {0.f, 0.f, 0.f, 0.f};
    of = MFMA_F16_16x16x16(kqA, vf, of);
#pragma unroll
    for (int kt = 0; kt < 4; kt++) {
      v4h Wh;
#pragma unroll
      for (int e = 0; e < 4; e++) Wh[e] = (_Float16)Wf[kt][e];
      of = MFMA_F16_16x16x16(qf[kt], Wh, of);
    }
#pragma unroll
    for (int kt = 0; kt < 4; kt++) Wf[kt] = MFMA_F16_16x16x16(ktf[kt], vf, Wf[kt]);

    const size_t ob = ((size_t)(b * L + segbase + c * 16 + 4 * g)) * DIM + h * 64 + dt * 16 + m;
#pragma unroll
    for (int e = 0; e < 4; e++) Vr[ob + (size_t)e * DIM] = f2h_us(of[e]);

    qg = qn; kg = kn; vg = vn; gb = gbn;
  }

  float* Dp = D + ((size_t)((b * 16 + h) * NSEG + seg)) * 4096;
#pragma unroll
  for (int kt = 0; kt < 4; kt++)
#pragma unroll
    for (int e = 0; e < 4; e++)
      Dp[(kt * 16 + 4 * g + e) * 64 + dt * 16 + m] = Wf[kt][e];
}

// ---------------------------------------------------------------------------
// Phase B: exclusive prefix over segments, seeded with W0.
// ---------------------------------------------------------------------------
__global__ __launch_bounds__(256) void prefix_D(float* __restrict__ D,
                                                const float* __restrict__ W0) {
  const int bh = blockIdx.x;
  const int h = bh & 15;
  const int tid = threadIdx.x;
  float p[16];
#pragma unroll
  for (int i = 0; i < 16; i++) p[i] = W0[(size_t)h * 4096 + tid + i * 256];
  for (int s = 0; s < NSEG; s++) {
    float* Dp = D + ((size_t)bh * NSEG + s) * 4096;
#pragma unroll
    for (int i = 0; i < 16; i++) {
      const float t = Dp[tid + i * 256];
      Dp[tid + i * 256] = p[i];
      p[i] += t;
    }
  }
}

// ---------------------------------------------------------------------------
// Phase C: o += qc @ P_seg.
// ---------------------------------------------------------------------------
__global__ __launch_bounds__(256) void apply_corr(const unsigned short* __restrict__ Qc,
                                                  const float* __restrict__ P,
                                                  unsigned short* __restrict__ Op) {
  const int seg = blockIdx.x & 15;
  const int h = (blockIdx.x >> 4) & 15;
  const int b = blockIdx.x >> 8;
  const int tid = threadIdx.x;
  const int lane = tid & 63;
  const int dt = tid >> 6;
  const int m = lane & 15;
  const int g = lane >> 4;

  __shared__ __align__(16) _Float16 Pt[64][72];
  __shared__ __align__(16) _Float16 qt[16][72];

  const float* Pp = P + ((size_t)((b * 16 + h) * NSEG + seg)) * 4096;
#pragma unroll
  for (int i = 0; i < 16; i++) {
    const int el = tid + i * 256;
    Pt[el & 63][el >> 6] = (_Float16)Pp[el];
  }
  __syncthreads();

  v4h pb[4];
#pragma unroll
  for (int kt = 0; kt < 4; kt++) pb[kt] = *(const v4h*)&Pt[dt * 16 + m][kt * 16 + 4 * g];

  const int srow = tid >> 4;
  const int scol = (tid & 15) * 4;
  for (int rt = 0; rt < 8; rt++) {
    const size_t gb = ((size_t)(b * L + seg * SEG_TOK + rt * 16 + srow)) * DIM + h * 64 + scol;
    const uint2 qg = *(const uint2*)(Qc + gb);
    __syncthreads();
    *(uint2*)&qt[srow][scol] = qg;
    __syncthreads();
    v4h qf[4];
#pragma unroll
    for (int kt = 0; kt < 4; kt++) qf[kt] = *(const v4h*)&qt[m][kt * 16 + 4 * g];
    v4f corr = {0.f, 0.f, 0.f, 0.f};
#pragma unroll
    for (int kt = 0; kt < 4; kt++) corr = MFMA_F16_16x16x16(qf[kt], pb[kt], corr);
    const size_t ob = ((size_t)(b * L + seg * SEG_TOK + rt * 16 + 4 * g)) * DIM + h * 64 + dt * 16 + m;
#pragma unroll
    for (int e = 0; e < 4; e++) {
      const float v = h2f_us(Op[ob + (size_t)e * DIM]) + corr[e];
      Op[ob + (size_t)e * DIM] = f2h_us(v);
    }
  }
}

// ---------------------------------------------------------------------------
// LayerNorm over dk=64 per head + gate multiply. O f16 -> bf16 in place.
// ---------------------------------------------------------------------------
__global__ __launch_bounds__(256) void ln_gate(unsigned short* __restrict__ Ob,
                                               const unsigned short* __restrict__ G,
                                               const float* __restrict__ gamma,
                                               const float* __restrict__ beta) {
  const int r = blockIdx.x;
  const int tid = threadIdx.x;
  const int c = tid * 4;
  float o[4];
  h4_unpack(*(const uint2*)(Ob + (size_t)r * DIM + c), o);
  float sum = o[0] + o[1] + o[2] + o[3];
#pragma unroll
  for (int off = 8; off >= 1; off >>= 1) sum += __shfl_xor(sum, off, 16);
  const float mu = sum * (1.f / 64.f);
  float d[4];
  float vs = 0.f;
#pragma unroll
  for (int e = 0; e < 4; e++) { d[e] = o[e] - mu; vs += d[e] * d[e]; }
#pragma unroll
  for (int off = 8; off >= 1; off >>= 1) vs += __shfl_xor(vs, off, 16);
  const float rstd = rsqrtf(vs * (1.f / 64.f) + 1e-5f);
  const int dl = c & 63;
  const float4 gm = *(const float4*)(gamma + dl);
  const float4 bt = *(const float4*)(beta + dl);
  float gt[4];
  u2_unpack(*(const uint2*)(G + (size_t)r * DIM + c), gt);
  float outv[4];
  outv[0] = (d[0] * rstd * gm.x + bt.x) * gt[0];
  outv[1] = (d[1] * rstd * gm.y + bt.y) * gt[1];
  outv[2] = (d[2] * rstd * gm.z + bt.z) * gt[2];
  outv[3] = (d[3] * rstd * gm.w + bt.w) * gt[3];
  uint2 u;
  u.x = (unsigned int)f2bf(outv[0]) | ((unsigned int)f2bf(outv[1]) << 16);
  u.y = (unsigned int)f2bf(outv[2]) | ((unsigned int)f2bf(outv[3]) << 16);
  *(uint2*)(Ob + (size_t)r * DIM + c) = u;
}

// ---------------------------------------------------------------------------
// ws: sA=qlin->qc(f16)->Wobf, sB=klin->gate, sC=vlin->o->o_ln
// d_out: Hbf [0,16.78M) -> D overlays after fused QKV; Wbf x4; side buffer.
// ---------------------------------------------------------------------------
extern "C" void kernel_launch(void* const* d_in, const int* in_sizes, int n_in,
                              void* d_out, int out_size, void* d_ws, size_t ws_size,
                              hipStream_t stream) {
  const float* H  = (const float*)d_in[0];
  const float* Wq = (const float*)d_in[1];
  const float* Wk = (const float*)d_in[2];
  const float* Wv = (const float*)d_in[3];
  const float* cq = (const float*)d_in[4];
  const float* ck = (const float*)d_in[5];
  const float* cv = (const float*)d_in[6];
  const float* W0 = (const float*)d_in[7];
  const float* gamma = (const float*)d_in[8];
  const float* beta  = (const float*)d_in[9];
  const float* Wg = (const float*)d_in[10];
  const float* Wo = (const float*)d_in[11];

  const size_t SZ = (size_t)ROWS * DIM;   // 8M elements
  const size_t WSZ = (size_t)DIM * DIM;   // 1M elements
  unsigned short* sA = (unsigned short*)d_ws;
  unsigned short* sB = sA + SZ;
  unsigned short* sC = sB + SZ;

  unsigned short* Hbf = (unsigned short*)d_out;  // dies before D
  unsigned short* Wbf = Hbf + SZ;                // Wq,Wk,Wv,Wg bf16
  unsigned short* side = Wbf + 4 * WSZ;
  unsigned short* sideQ = side;
  unsigned short* sideK = side + (size_t)192 * DIM;
  unsigned short* sideV = side + (size_t)384 * DIM;
  float* D = (float*)d_out;                      // overlays Hbf

  cvt_f2b<<<SZ / 1024, 256, 0, stream>>>(H, Hbf);
  cvt_w4<<<4096, 256, 0, stream>>>(Wq, Wk, Wv, Wg, Wbf);

  // fused q/k/v projection: N=3072, outputs split to sA/sB/sC by bn>>10
  gemm_a<0><<<dim3(24, 64), 256, 0, stream>>>(Hbf, Wbf, sA);

  copy_side<<<192, 256, 0, stream>>>(sA, sB, sC, sideQ, sideK, sideV);

  scan_seg<<<1024, 256, 0, stream>>>(sA, sB, sC, sideQ, sideK, sideV,
                                     cq, ck, cv, D);

  gemm_gate<<<dim3(8, 64), 256, 0, stream>>>(H, Wbf + 3 * WSZ, sB);  // gate

  prefix_D<<<64, 256, 0, stream>>>(D, W0);

  apply_corr<<<1024, 256, 0, stream>>>(sA, D, sC);

  ln_gate<<<ROWS, 256, 0, stream>>>(sC, sB, gamma, beta);

  cvt_f2b<<<WSZ / 1024, 256, 0, stream>>>(Wo, sA);  // Wo bf16 -> sA (qc dead)

  gemm_a<1><<<dim3(8, 64), 256, 0, stream>>>(sC, sA, d_out);  // fp32 output
}

// Round 9
// 287.744 us; speedup vs baseline: 1.9574x; 1.1249x over previous
//
#include <hip/hip_runtime.h>

#define L 2048
#define DIM 1024
#define ROWS 8192     // b*l
#define NSEG 16       // segments per sequence
#define SEG_CHUNKS 8  // chunks per segment
#define SEG_TOK 128   // tokens per segment

typedef __attribute__((ext_vector_type(4))) _Float16 v4h;
typedef __attribute__((ext_vector_type(4))) float v4f;
typedef __attribute__((ext_vector_type(8))) short v8s;

#if defined(__HIP_DEVICE_COMPILE__)
#define MFMA_F16_16x16x16(a, b, c) __builtin_amdgcn_mfma_f32_16x16x16f16((a), (b), (c), 0, 0, 0)
#define MFMA_BF16_16x16x32(a, b, c) __builtin_amdgcn_mfma_f32_16x16x32_bf16((a), (b), (c), 0, 0, 0)
#else
#define MFMA_F16_16x16x16(a, b, c) (c)
#define MFMA_BF16_16x16x32(a, b, c) (c)
#endif

// async global->LDS, 16B/lane; LDS dest = wave-uniform base + lane*16
__device__ inline void gld16(const unsigned short* g, unsigned short* l) {
#if defined(__HIP_DEVICE_COMPILE__)
  __builtin_amdgcn_global_load_lds(
      (__attribute__((address_space(1))) void*)g,
      (__attribute__((address_space(3))) void*)l, 16, 0, 0);
#endif
}

__device__ inline unsigned short f2bf(float f) {
  unsigned int u = __float_as_uint(f);
  unsigned int r = (u + 0x7fffu + ((u >> 16) & 1u)) >> 16;
  return (unsigned short)r;
}
__device__ inline void u2_unpack(const uint2 u, float* f) {  // bf16 x4
  f[0] = __uint_as_float((u.x & 0xffffu) << 16);
  f[1] = __uint_as_float(u.x & 0xffff0000u);
  f[2] = __uint_as_float((u.y & 0xffffu) << 16);
  f[3] = __uint_as_float(u.y & 0xffff0000u);
}
__device__ inline uint4 pack8(const float4 a, const float4 b) {
  uint4 u;
  u.x = (unsigned int)f2bf(a.x) | ((unsigned int)f2bf(a.y) << 16);
  u.y = (unsigned int)f2bf(a.z) | ((unsigned int)f2bf(a.w) << 16);
  u.z = (unsigned int)f2bf(b.x) | ((unsigned int)f2bf(b.y) << 16);
  u.w = (unsigned int)f2bf(b.z) | ((unsigned int)f2bf(b.w) << 16);
  return u;
}
__device__ inline unsigned short f2h_us(float f) {
  _Float16 h = (_Float16)f;
  unsigned short u;
  __builtin_memcpy(&u, &h, 2);
  return u;
}
__device__ inline float h2f_us(unsigned short u) {
  _Float16 h;
  __builtin_memcpy(&h, &u, 2);
  return (float)h;
}
__device__ inline void h4_unpack(const uint2 u, float* f) {  // f16 x4
  f[0] = h2f_us((unsigned short)(u.x & 0xffffu));
  f[1] = h2f_us((unsigned short)(u.x >> 16));
  f[2] = h2f_us((unsigned short)(u.y & 0xffffu));
  f[3] = h2f_us((unsigned short)(u.y >> 16));
}

// ---------------------------------------------------------------------------
// One-shot fp32->bf16: H (2M float4) then Wq,Wk,Wv,Wg (256K float4 each).
// ---------------------------------------------------------------------------
__global__ __launch_bounds__(256) void cvt_all(const float* __restrict__ H,
                                               const float* __restrict__ w0,
                                               const float* __restrict__ w1,
                                               const float* __restrict__ w2,
                                               const float* __restrict__ w3,
                                               unsigned short* __restrict__ Hbf,
                                               unsigned short* __restrict__ Wbf) {
  const int i = blockIdx.x * 256 + threadIdx.x;  // float4 index
  const float* s;
  unsigned short* d;
  int li;
  if (i < 2097152) {
    s = H; d = Hbf; li = i;
  } else {
    const int j = i - 2097152;
    const int w = j >> 18;          // 262144 float4 per weight
    li = j & 262143;
    s = (w == 0) ? w0 : (w == 1) ? w1 : (w == 2) ? w2 : w3;
    d = Wbf + (size_t)w * DIM * DIM;
  }
  const float4 v = ((const float4*)s)[li];
  uint2 u;
  u.x = (unsigned int)f2bf(v.x) | ((unsigned int)f2bf(v.y) << 16);
  u.y = (unsigned int)f2bf(v.z) | ((unsigned int)f2bf(v.w) << 16);
  ((uint2*)d)[li] = u;
}

__global__ __launch_bounds__(256) void cvt_f2b(const float* __restrict__ s,
                                               unsigned short* __restrict__ d) {
  const int i = blockIdx.x * 256 + threadIdx.x;
  const float4 v = ((const float4*)s)[i];
  uint2 u;
  u.x = (unsigned int)f2bf(v.x) | ((unsigned int)f2bf(v.y) << 16);
  u.y = (unsigned int)f2bf(v.z) | ((unsigned int)f2bf(v.w) << 16);
  ((uint2*)d)[i] = u;
}

// ---------------------------------------------------------------------------
// m97-style GEMM: C = A[M,K] @ B[N,K]^T, bf16, BK=64, 128x128 tile,
// global_load_lds w16 staging, XOR-swizzled LDS (0 bank conflicts).
// Output buffer selected by bn>>10 (fused multi-weight); OUTF32 = fp32 out.
// ---------------------------------------------------------------------------
template <int OUTF32>
__global__ __launch_bounds__(256) void gemm_a(const unsigned short* __restrict__ A,
                                              const unsigned short* __restrict__ B,
                                              unsigned short* __restrict__ o0,
                                              unsigned short* __restrict__ o1,
                                              unsigned short* __restrict__ o2,
                                              unsigned short* __restrict__ o3) {
  __shared__ __align__(16) unsigned short As[128 * 64];
  __shared__ __align__(16) unsigned short Bs[128 * 64];
  const int tid = threadIdx.x;
  const int bm = blockIdx.y * 128;
  const int bn = blockIdx.x * 128;
  const int wave = tid >> 6;
  const int lane = tid & 63;
  const int m16 = lane & 15;
  const int g = lane >> 4;
  const int wm = (wave >> 1) * 64;
  const int wn = (wave & 1) * 64;
  const int srow8 = lane >> 3;
  const int schk = lane & 7;

  v4f acc[4][4];
#pragma unroll
  for (int i = 0; i < 4; i++)
#pragma unroll
    for (int j = 0; j < 4; j++) acc[i][j] = (v4f){0.f, 0.f, 0.f, 0.f};

  for (int kt = 0; kt < DIM; kt += 64) {
    __syncthreads();
#pragma unroll
    for (int j = 0; j < 4; j++) {
      const int r = wave * 32 + j * 8 + srow8;
      const int cg = schk ^ (r & 7);
      gld16(A + (size_t)(bm + r) * DIM + kt + cg * 8, &As[(wave * 32 + j * 8) * 64]);
      gld16(B + (size_t)(bn + r) * DIM + kt + cg * 8, &Bs[(wave * 32 + j * 8) * 64]);
    }
    __syncthreads();
#pragma unroll
    for (int kh = 0; kh < 2; kh++) {
      v8s af[4], bf[4];
#pragma unroll
      for (int i = 0; i < 4; i++) {
        const int r = wm + i * 16 + m16;
        af[i] = *(const v8s*)&As[r * 64 + (((kh * 4 + g) ^ (r & 7)) * 8)];
      }
#pragma unroll
      for (int j = 0; j < 4; j++) {
        const int r = wn + j * 16 + m16;
        bf[j] = *(const v8s*)&Bs[r * 64 + (((kh * 4 + g) ^ (r & 7)) * 8)];
      }
#pragma unroll
      for (int i = 0; i < 4; i++)
#pragma unroll
        for (int j = 0; j < 4; j++) acc[i][j] = MFMA_BF16_16x16x32(af[i], bf[j], acc[i][j]);
    }
  }

  const int t = bn >> 10;
  const int cb = bn & 1023;
  unsigned short* C = (t == 0) ? o0 : (t == 1) ? o1 : (t == 2) ? o2 : o3;
#pragma unroll
  for (int i = 0; i < 4; i++)
#pragma unroll
    for (int e = 0; e < 4; e++) {
      const size_t row = (size_t)(bm + wm + i * 16 + 4 * g + e);
#pragma unroll
      for (int j = 0; j < 4; j++) {
        const size_t idx = row * DIM + cb + wn + j * 16 + m16;
        if (OUTF32)
          ((float*)o0)[idx] = acc[i][j][e];
        else
          C[idx] = f2bf(acc[i][j][e]);
      }
    }
}

// ---------------------------------------------------------------------------
// Fallback gate GEMM (A = fp32 H, pack in staging). Used when ws is small.
// ---------------------------------------------------------------------------
__global__ __launch_bounds__(256) void gemm_gate(const float* __restrict__ Af,
                                                 const unsigned short* __restrict__ Bf,
                                                 unsigned short* __restrict__ C) {
  __shared__ __align__(16) unsigned short As[128][40];
  __shared__ __align__(16) unsigned short Bs[128][40];
  const int tid = threadIdx.x;
  const int bm = blockIdx.y * 128;
  const int bn = blockIdx.x * 128;
  const int wave = tid >> 6;
  const int lane = tid & 63;
  const int m16 = lane & 15;
  const int g = lane >> 4;
  const int wm = (wave >> 1) * 64;
  const int wn = (wave & 1) * 64;
  const int lr = tid >> 2;
  const int lc = (tid & 3) * 8;

  v4f acc[4][4];
#pragma unroll
  for (int i = 0; i < 4; i++)
#pragma unroll
    for (int j = 0; j < 4; j++) acc[i][j] = (v4f){0.f, 0.f, 0.f, 0.f};

  auto loadAB = [&](int kt, uint4& a0, uint4& a1, uint4& b0, uint4& b1) {
    const float* p0 = Af + (size_t)(bm + lr) * DIM + lc + kt;
    const float* p1 = Af + (size_t)(bm + 64 + lr) * DIM + lc + kt;
    a0 = pack8(*(const float4*)p0, *(const float4*)(p0 + 4));
    a1 = pack8(*(const float4*)p1, *(const float4*)(p1 + 4));
    b0 = *(const uint4*)(Bf + (size_t)(bn + lr) * DIM + lc + kt);
    b1 = *(const uint4*)(Bf + (size_t)(bn + 64 + lr) * DIM + lc + kt);
  };

  uint4 a0, a1, b0, b1;
  loadAB(0, a0, a1, b0, b1);

  for (int kt = 0; kt < DIM; kt += 32) {
    __syncthreads();
    *(uint4*)&As[lr][lc] = a0;
    *(uint4*)&As[64 + lr][lc] = a1;
    *(uint4*)&Bs[lr][lc] = b0;
    *(uint4*)&Bs[64 + lr][lc] = b1;
    __syncthreads();
    if (kt + 32 < DIM) loadAB(kt + 32, a0, a1, b0, b1);
    v8s af[4], bf[4];
#pragma unroll
    for (int i = 0; i < 4; i++) af[i] = *(const v8s*)&As[wm + i * 16 + m16][g * 8];
#pragma unroll
    for (int j = 0; j < 4; j++) bf[j] = *(const v8s*)&Bs[wn + j * 16 + m16][g * 8];
#pragma unroll
    for (int i = 0; i < 4; i++)
#pragma unroll
      for (int j = 0; j < 4; j++) acc[i][j] = MFMA_BF16_16x16x32(af[i], bf[j], acc[i][j]);
  }

#pragma unroll
  for (int i = 0; i < 4; i++)
#pragma unroll
    for (int e = 0; e < 4; e++) {
      const size_t row = (size_t)(bm + wm + i * 16 + 4 * g + e);
#pragma unroll
      for (int j = 0; j < 4; j++)
        C[row * DIM + bn + wn + j * 16 + m16] = f2bf(acc[i][j][e]);
    }
}

// ---------------------------------------------------------------------------
// Copy 3 pre-segment boundary rows of raw q/k/v linears to a side buffer.
// ---------------------------------------------------------------------------
__global__ __launch_bounds__(256) void copy_side(const unsigned short* __restrict__ Q,
                                                 const unsigned short* __restrict__ K,
                                                 const unsigned short* __restrict__ V,
                                                 unsigned short* __restrict__ sQ,
                                                 unsigned short* __restrict__ sK,
                                                 unsigned short* __restrict__ sV) {
  const int idx = blockIdx.x;
  const int j = idx % 3;
  const int bs = idx / 3;
  const int seg = bs & 15;
  const int b = bs >> 4;
  const int ch = threadIdx.x * 4;
  const size_t so = ((size_t)(bs * 3 + j)) * DIM + ch;
  if (seg == 0) {
    const uint2 z = {0u, 0u};
    *(uint2*)(sQ + so) = z;
    *(uint2*)(sK + so) = z;
    *(uint2*)(sV + so) = z;
  } else {
    const size_t go = ((size_t)(b * L + seg * SEG_TOK - 3 + j)) * DIM + ch;
    *(uint2*)(sQ + so) = *(const uint2*)(Q + go);
    *(uint2*)(sK + so) = *(const uint2*)(K + go);
    *(uint2*)(sV + so) = *(const uint2*)(V + go);
  }
}

// ---------------------------------------------------------------------------
// Phase A: segmented fused conv+SiLU(+L2norm) + local Titans scan from W=0.
// ---------------------------------------------------------------------------
__global__ __launch_bounds__(256) void scan_seg(unsigned short* __restrict__ Qr,
                                                const unsigned short* __restrict__ Kr,
                                                unsigned short* __restrict__ Vr,
                                                const unsigned short* __restrict__ sQ,
                                                const unsigned short* __restrict__ sK,
                                                const unsigned short* __restrict__ sV,
                                                const float* __restrict__ CWq,
                                                const float* __restrict__ CWk,
                                                const float* __restrict__ CWv,
                                                float* __restrict__ D) {
  const int seg = blockIdx.x & 15;
  const int h = (blockIdx.x >> 4) & 15;
  const int b = blockIdx.x >> 8;
  const int tid = threadIdx.x;
  const int lane = tid & 63;
  const int dt = tid >> 6;
  const int m = lane & 15;
  const int g = lane >> 4;
  const int segbase = seg * SEG_TOK;

  __shared__ __align__(16) unsigned short rq[32][68];
  __shared__ __align__(16) unsigned short rk[32][68];
  __shared__ __align__(16) unsigned short rv[32][68];
  __shared__ __align__(16) _Float16 qs[16][72];
  __shared__ __align__(16) _Float16 ks[16][72];
  __shared__ __align__(16) _Float16 kts[64][20];
  __shared__ __align__(16) _Float16 vts[64][20];

  v4f Wf[4];
#pragma unroll
  for (int kt = 0; kt < 4; kt++) Wf[kt] = (v4f){0.f, 0.f, 0.f, 0.f};

  const int srow = tid >> 4;
  const int scol = (tid & 15) * 4;
  const size_t gcol = (size_t)h * 64 + scol;

  float wq[4][4], wk[4][4], wv[4][4];
#pragma unroll
  for (int e = 0; e < 4; e++) {
    const float4 a = *(const float4*)(CWq + (gcol + e) * 4);
    const float4 bw = *(const float4*)(CWk + (gcol + e) * 4);
    const float4 cw = *(const float4*)(CWv + (gcol + e) * 4);
    wq[e][0] = a.x; wq[e][1] = a.y; wq[e][2] = a.z; wq[e][3] = a.w;
    wk[e][0] = bw.x; wk[e][1] = bw.y; wk[e][2] = bw.z; wk[e][3] = bw.w;
    wv[e][0] = cw.x; wv[e][1] = cw.y; wv[e][2] = cw.z; wv[e][3] = cw.w;
  }

  if (tid < 48) {
    const int j = tid >> 4;
    const int sc = (tid & 15) * 4;
    const size_t so = ((size_t)((b * NSEG + seg) * 3 + j)) * DIM + h * 64 + sc;
    const int slot = (29 + j);
    *(uint2*)&rq[slot][sc] = *(const uint2*)(sQ + so);
    *(uint2*)&rk[slot][sc] = *(const uint2*)(sK + so);
    *(uint2*)&rv[slot][sc] = *(const uint2*)(sV + so);
  }

  size_t gb = ((size_t)(b * L + segbase + srow)) * DIM + gcol;
  uint2 qg = *(const uint2*)(Qr + gb);
  uint2 kg = *(const uint2*)(Kr + gb);
  uint2 vg = *(const uint2*)(Vr + gb);

  for (int c = 0; c < SEG_CHUNKS; c++) {
    const int t = segbase + c * 16 + srow;
    __syncthreads();
    *(uint2*)&rq[t & 31][scol] = qg;
    *(uint2*)&rk[t & 31][scol] = kg;
    *(uint2*)&rv[t & 31][scol] = vg;
    const int cn = (c + 1 < SEG_CHUNKS) ? c + 1 : c;
    const size_t gbn = ((size_t)(b * L + segbase + cn * 16 + srow)) * DIM + gcol;
    const uint2 qn = *(const uint2*)(Qr + gbn);
    const uint2 kn = *(const uint2*)(Kr + gbn);
    const uint2 vn = *(const uint2*)(Vr + gbn);
    __syncthreads();

    float sq[4], sk[4], sv[4];
    {
      float q0[4], q1[4], q2[4], q3[4];
      float k0[4], k1[4], k2[4], k3[4];
      float v0[4], v1[4], v2[4], v3[4];
      u2_unpack(qg, q0);
      u2_unpack(kg, k0);
      u2_unpack(vg, v0);
      u2_unpack(*(const uint2*)&rq[(t - 1) & 31][scol], q1);
      u2_unpack(*(const uint2*)&rk[(t - 1) & 31][scol], k1);
      u2_unpack(*(const uint2*)&rv[(t - 1) & 31][scol], v1);
      u2_unpack(*(const uint2*)&rq[(t - 2) & 31][scol], q2);
      u2_unpack(*(const uint2*)&rk[(t - 2) & 31][scol], k2);
      u2_unpack(*(const uint2*)&rv[(t - 2) & 31][scol], v2);
      u2_unpack(*(const uint2*)&rq[(t - 3) & 31][scol], q3);
      u2_unpack(*(const uint2*)&rk[(t - 3) & 31][scol], k3);
      u2_unpack(*(const uint2*)&rv[(t - 3) & 31][scol], v3);
#pragma unroll
      for (int e = 0; e < 4; e++) {
        const float yq = q0[e] + wq[e][0] * q3[e] + wq[e][1] * q2[e] + wq[e][2] * q1[e] + wq[e][3] * q0[e];
        const float yk = k0[e] + wk[e][0] * k3[e] + wk[e][1] * k2[e] + wk[e][2] * k1[e] + wk[e][3] * k0[e];
        const float yv = v0[e] + wv[e][0] * v3[e] + wv[e][1] * v2[e] + wv[e][2] * v1[e] + wv[e][3] * v0[e];
        sq[e] = yq / (1.f + __expf(-yq));
        sk[e] = yk / (1.f + __expf(-yk));
        sv[e] = yv / (1.f + __expf(-yv));
      }
    }
    float ssq = sq[0] * sq[0] + sq[1] * sq[1] + sq[2] * sq[2] + sq[3] * sq[3];
    float ssk = sk[0] * sk[0] + sk[1] * sk[1] + sk[2] * sk[2] + sk[3] * sk[3];
#pragma unroll
    for (int off = 8; off >= 1; off >>= 1) {
      ssq += __shfl_xor(ssq, off, 16);
      ssk += __shfl_xor(ssk, off, 16);
    }
    const float scq = rsqrtf(ssq + 1e-12f);
    const float sck = rsqrtf(ssk + 1e-12f);

    const v4h qh = {(_Float16)(sq[0] * scq), (_Float16)(sq[1] * scq),
                    (_Float16)(sq[2] * scq), (_Float16)(sq[3] * scq)};
    const v4h kh = {(_Float16)(sk[0] * sck), (_Float16)(sk[1] * sck),
                    (_Float16)(sk[2] * sck), (_Float16)(sk[3] * sck)};
    *(v4h*)&qs[srow][scol] = qh;
    *(v4h*)&ks[srow][scol] = kh;
    kts[scol + 0][srow] = kh[0]; kts[scol + 1][srow] = kh[1];
    kts[scol + 2][srow] = kh[2]; kts[scol + 3][srow] = kh[3];
    vts[scol + 0][srow] = (_Float16)sv[0]; vts[scol + 1][srow] = (_Float16)sv[1];
    vts[scol + 2][srow] = (_Float16)sv[2]; vts[scol + 3][srow] = (_Float16)sv[3];

    uint2 qp;
    __builtin_memcpy(&qp, &qh, 8);
    *(uint2*)(Qr + gb) = qp;  // qc (f16) for the correction pass

    __syncthreads();

    v4h qf[4], kf[4], ktf[4];
#pragma unroll
    for (int kt = 0; kt < 4; kt++) {
      qf[kt] = *(const v4h*)&qs[m][kt * 16 + 4 * g];
      kf[kt] = *(const v4h*)&ks[m][kt * 16 + 4 * g];
      ktf[kt] = *(const v4h*)&kts[kt * 16 + m][4 * g];
    }
    const v4h vf = *(const v4h*)&vts[dt * 16 + m][4 * g];

    v4f kq = {0.f, 0.f, 0.f, 0.f};
#pragma unroll
    for (int kt = 0; kt < 4; kt++) kq = MFMA_F16_16x16x16(kf[kt], qf[kt], kq);

    v4h kqA;
#pragma unroll
    for (int e = 0; e < 4; e++)
      kqA[e] = (4 * g + e <= m) ? (_Float16)kq[e] : (_Float16)0.f;

    v4f of = {0.f, 0.f, 0.f, 0.f};
    of = MFMA_F16_16x16x16(kqA, vf, of);
#pragma unroll
    for (int kt = 0; kt < 4; kt++) {
      v4h Wh;
#pragma unroll
      for (int e = 0; e < 4; e++) Wh[e] = (_Float16)Wf[kt][e];
      of = MFMA_F16_16x16x16(qf[kt], Wh, of);
    }
#pragma unroll
    for (int kt = 0; kt < 4; kt++) Wf[kt] = MFMA_F16_16x16x16(ktf[kt], vf, Wf[kt]);

    const size_t ob = ((size_t)(b * L + segbase + c * 16 + 4 * g)) * DIM + h * 64 + dt * 16 + m;
#pragma unroll
    for (int e = 0; e < 4; e++) Vr[ob + (size_t)e * DIM] = f2h_us(of[e]);

    qg = qn; kg = kn; vg = vn; gb = gbn;
  }

  float* Dp = D + ((size_t)((b * 16 + h) * NSEG + seg)) * 4096;
#pragma unroll
  for (int kt = 0; kt < 4; kt++)
#pragma unroll
    for (int e = 0; e < 4; e++)
      Dp[(kt * 16 + 4 * g + e) * 64 + dt * 16 + m] = Wf[kt][e];
}

// ---------------------------------------------------------------------------
// Phase B: exclusive prefix over segments, seeded with W0.
// ---------------------------------------------------------------------------
__global__ __launch_bounds__(256) void prefix_D(float* __restrict__ D,
                                                const float* __restrict__ W0) {
  const int bh = blockIdx.x;
  const int h = bh & 15;
  const int tid = threadIdx.x;
  float p[16];
#pragma unroll
  for (int i = 0; i < 16; i++) p[i] = W0[(size_t)h * 4096 + tid + i * 256];
  for (int s = 0; s < NSEG; s++) {
    float* Dp = D + ((size_t)bh * NSEG + s) * 4096;
#pragma unroll
    for (int i = 0; i < 16; i++) {
      const float t = Dp[tid + i * 256];
      Dp[tid + i * 256] = p[i];
      p[i] += t;
    }
  }
}

// ---------------------------------------------------------------------------
// Phase C fused with epilogue: o_full = o_partial + qc @ P_seg, then
// LayerNorm(dk=64) * gate, written bf16 in place over o. grid 1024; block 256.
// ---------------------------------------------------------------------------
__global__ __launch_bounds__(256) void corr_ln_gate(const unsigned short* __restrict__ Qc,
                                                    const float* __restrict__ P,
                                                    unsigned short* __restrict__ Op,
                                                    const unsigned short* __restrict__ G,
                                                    const float* __restrict__ gamma,
                                                    const float* __restrict__ beta) {
  const int seg = blockIdx.x & 15;
  const int h = (blockIdx.x >> 4) & 15;
  const int b = blockIdx.x >> 8;
  const int tid = threadIdx.x;
  const int lane = tid & 63;
  const int dt = tid >> 6;
  const int m = lane & 15;
  const int g = lane >> 4;

  __shared__ __align__(16) _Float16 Pt[64][72];
  __shared__ __align__(16) _Float16 qt[16][72];
  __shared__ __align__(16) float ot[16][68];

  const float* Pp = P + ((size_t)((b * 16 + h) * NSEG + seg)) * 4096;
#pragma unroll
  for (int i = 0; i < 16; i++) {
    const int el = tid + i * 256;
    Pt[el & 63][el >> 6] = (_Float16)Pp[el];
  }
  __syncthreads();

  // B-frag of P: pb[kt][e] = P[kt*16+4g+e][dt*16+m]
  v4h pb[4];
#pragma unroll
  for (int kt = 0; kt < 4; kt++) pb[kt] = *(const v4h*)&Pt[dt * 16 + m][kt * 16 + 4 * g];

  const int srow = tid >> 4;
  const int scol = (tid & 15) * 4;
  const float4 gm = *(const float4*)(gamma + scol);
  const float4 bt = *(const float4*)(beta + scol);

  for (int rt = 0; rt < 8; rt++) {
    const int row0 = seg * SEG_TOK + rt * 16;
    const size_t gb = ((size_t)(b * L + row0 + srow)) * DIM + h * 64 + scol;
    const uint2 qg = *(const uint2*)(Qc + gb);
    __syncthreads();  // previous iteration done with qt/ot
    *(uint2*)&qt[srow][scol] = qg;
    __syncthreads();
    v4h qf[4];
#pragma unroll
    for (int kt = 0; kt < 4; kt++) qf[kt] = *(const v4h*)&qt[m][kt * 16 + 4 * g];
    v4f corr = {0.f, 0.f, 0.f, 0.f};
#pragma unroll
    for (int kt = 0; kt < 4; kt++) corr = MFMA_F16_16x16x16(qf[kt], pb[kt], corr);
    // o_full into LDS (C-layout positions)
    const size_t ob = ((size_t)(b * L + row0 + 4 * g)) * DIM + h * 64 + dt * 16 + m;
#pragma unroll
    for (int e = 0; e < 4; e++)
      ot[4 * g + e][dt * 16 + m] = h2f_us(Op[ob + (size_t)e * DIM]) + corr[e];
    __syncthreads();
    // LN over the 64 head cols of row srow + gate multiply
    const float4 ov = *(const float4*)&ot[srow][scol];
    float sum = ov.x + ov.y + ov.z + ov.w;
#pragma unroll
    for (int off = 8; off >= 1; off >>= 1) sum += __shfl_xor(sum, off, 16);
    const float mu = sum * (1.f / 64.f);
    const float d0 = ov.x - mu, d1 = ov.y - mu, d2 = ov.z - mu, d3 = ov.w - mu;
    float vs = d0 * d0 + d1 * d1 + d2 * d2 + d3 * d3;
#pragma unroll
    for (int off = 8; off >= 1; off >>= 1) vs += __shfl_xor(vs, off, 16);
    const float rstd = rsqrtf(vs * (1.f / 64.f) + 1e-5f);
    float gt[4];
    u2_unpack(*(const uint2*)(G + gb), gt);
    float outv[4];
    outv[0] = (d0 * rstd * gm.x + bt.x) * gt[0];
    outv[1] = (d1 * rstd * gm.y + bt.y) * gt[1];
    outv[2] = (d2 * rstd * gm.z + bt.z) * gt[2];
    outv[3] = (d3 * rstd * gm.w + bt.w) * gt[3];
    uint2 u;
    u.x = (unsigned int)f2bf(outv[0]) | ((unsigned int)f2bf(outv[1]) << 16);
    u.y = (unsigned int)f2bf(outv[2]) | ((unsigned int)f2bf(outv[3]) << 16);
    *(uint2*)(Op + gb) = u;
  }
}

// ---------------------------------------------------------------------------
// Two layouts depending on ws_size (constant per process -> graph-safe):
// BIG (ws >= 59.9 MB): ws = sA,sB,sC,Wbf(4),side; d_out = Hbf->D | gate(bf16).
//   QKV+gate fused in one N=4096 GEMM.
// SMALL: round-8 layout; separate gemm_gate from fp32 H.
// ---------------------------------------------------------------------------
extern "C" void kernel_launch(void* const* d_in, const int* in_sizes, int n_in,
                              void* d_out, int out_size, void* d_ws, size_t ws_size,
                              hipStream_t stream) {
  const float* H  = (const float*)d_in[0];
  const float* Wq = (const float*)d_in[1];
  const float* Wk = (const float*)d_in[2];
  const float* Wv = (const float*)d_in[3];
  const float* cq = (const float*)d_in[4];
  const float* ck = (const float*)d_in[5];
  const float* cv = (const float*)d_in[6];
  const float* W0 = (const float*)d_in[7];
  const float* gamma = (const float*)d_in[8];
  const float* beta  = (const float*)d_in[9];
  const float* Wg = (const float*)d_in[10];
  const float* Wo = (const float*)d_in[11];

  const size_t SZ = (size_t)ROWS * DIM;   // 8M elements
  const size_t WSZ = (size_t)DIM * DIM;   // 1M elements
  const size_t SIDE = (size_t)192 * DIM;  // per side tensor
  unsigned short* sA = (unsigned short*)d_ws;
  unsigned short* sB = sA + SZ;
  unsigned short* sC = sB + SZ;

  const bool bigws = ws_size >= (3 * SZ + 4 * WSZ + 3 * SIDE) * 2;

  unsigned short* Hbf = (unsigned short*)d_out;
  float* D = (float*)d_out;  // overlays Hbf after QKV GEMM

  if (bigws) {
    unsigned short* Wbf = sC + SZ;              // ws tail
    unsigned short* side = Wbf + 4 * WSZ;
    unsigned short* gate = Hbf + SZ;            // d_out upper half (bf16)

    cvt_all<<<12288, 256, 0, stream>>>(H, Wq, Wk, Wv, Wg, Hbf, Wbf);
    // fused q/k/v/gate projection: N=4096
    gemm_a<0><<<dim3(32, 64), 256, 0, stream>>>(Hbf, Wbf, sA, sB, sC, gate);
    copy_side<<<192, 256, 0, stream>>>(sA, sB, sC, side, side + SIDE, side + 2 * SIDE);
    scan_seg<<<1024, 256, 0, stream>>>(sA, sB, sC, side, side + SIDE, side + 2 * SIDE,
                                       cq, ck, cv, D);
    prefix_D<<<64, 256, 0, stream>>>(D, W0);
    corr_ln_gate<<<1024, 256, 0, stream>>>(sA, D, sC, gate, gamma, beta);
    cvt_f2b<<<WSZ / 1024, 256, 0, stream>>>(Wo, sA);  // Wo bf16 (qc dead)
    gemm_a<1><<<dim3(8, 64), 256, 0, stream>>>(sC, sA, (unsigned short*)d_out,
                                               nullptr, nullptr, nullptr);
  } else {
    unsigned short* Wbf = Hbf + SZ;             // d_out tail
    unsigned short* side = Wbf + 4 * WSZ;

    cvt_all<<<12288, 256, 0, stream>>>(H, Wq, Wk, Wv, Wg, Hbf, Wbf);
    gemm_a<0><<<dim3(24, 64), 256, 0, stream>>>(Hbf, Wbf, sA, sB, sC, nullptr);
    copy_side<<<192, 256, 0, stream>>>(sA, sB, sC, side, side + SIDE, side + 2 * SIDE);
    scan_seg<<<1024, 256, 0, stream>>>(sA, sB, sC, side, side + SIDE, side + 2 * SIDE,
                                       cq, ck, cv, D);
    gemm_gate<<<dim3(8, 64), 256, 0, stream>>>(H, Wbf + 3 * WSZ, sB);  // gate
    prefix_D<<<64, 256, 0, stream>>>(D, W0);
    corr_ln_gate<<<1024, 256, 0, stream>>>(sA, D, sC, sB, gamma, beta);
    cvt_f2b<<<WSZ / 1024, 256, 0, stream>>>(Wo, sA);
    gemm_a<1><<<dim3(8, 64), 256, 0, stream>>>(sC, sA, (unsigned short*)d_out,
                                               nullptr, nullptr, nullptr);
  }
}